// Round 2
// baseline (8401.645 us; speedup 1.0000x reference)
//
#include <hip/hip_runtime.h>
#include <hip/hip_bf16.h>

#define N_NODES 50000
#define N_EDGES 800000
#define N_GRAPHS 32
#define NODE_DIM 128
#define HIDDEN 256
#define N_LAYERS 3

__device__ __forceinline__ float swish_f(float v) {
    // v * sigmoid(v) = v / (1 + exp(-v))
    return v / (1.0f + __expf(-v));
}

__device__ __forceinline__ void fma4(float* acc, float a, float4 wv) {
    acc[0] += a * wv.x;
    acc[1] += a * wv.y;
    acc[2] += a * wv.z;
    acc[3] += a * wv.w;
}

// d2[e] = |pos[dst] - pos[src] + shift @ lattice[batch[src]]|^2
__global__ void prep_kernel(const float* __restrict__ pos, const float* __restrict__ shift,
                            const float* __restrict__ lattice, const int* __restrict__ eidx,
                            const int* __restrict__ batch, float* __restrict__ d2) {
    int e = blockIdx.x * blockDim.x + threadIdx.x;
    if (e >= N_EDGES) return;
    int s = eidx[e];
    int d = eidx[N_EDGES + e];
    int b = batch[s];
    const float* lat = lattice + b * 9;
    float s0 = shift[e * 3 + 0], s1 = shift[e * 3 + 1], s2 = shift[e * 3 + 2];
    float acc = 0.f;
#pragma unroll
    for (int j = 0; j < 3; j++) {
        float v = pos[d * 3 + j] - pos[s * 3 + j] + s0 * lat[j] + s1 * lat[3 + j] + s2 * lat[6 + j];
        acc += v * v;
    }
    d2[e] = acc;
}

// x[n][c] = embed[z[n]][c]
__global__ void embed_kernel(const float* __restrict__ emb, const int* __restrict__ z,
                             float* __restrict__ x) {
    int i = blockIdx.x * blockDim.x + threadIdx.x;  // over N*128
    int n = i >> 7, c = i & 127;
    x[i] = emb[z[n] * 128 + c];
}

// Fused edge MLP: m = swish(swish(concat(x[dst],x[src],d2) @ W1 + b1) @ W2 + b2)
// then atomic scatter-add into agg[dst].
__global__ __launch_bounds__(256, 2) void edge_mlp_kernel(
    const float* __restrict__ x, const float* __restrict__ d2,
    const int* __restrict__ eidx,
    const float* __restrict__ W1, const float* __restrict__ b1,
    const float* __restrict__ W2, const float* __restrict__ b2,
    float* __restrict__ agg) {
    __shared__ float A[32][260];   // [edge][257]: 0:128 x[dst], 128:256 x[src], 256 d2
    __shared__ float M[32][260];   // [edge][256] hidden after swish
    __shared__ int s_dst[32];
    const int tid = threadIdx.x;
    const int e0 = blockIdx.x * 32;

    // ---- stage A tile: 8 threads per edge, float4 gathers ----
    {
        int el = tid >> 3;
        int j = tid & 7;
        int ge = e0 + el;
        int s = eidx[ge];
        int d = eidx[N_EDGES + ge];
        if (j == 0) {
            s_dst[el] = d;
            A[el][256] = d2[ge];
        }
        const float4* xd = (const float4*)(x + (size_t)d * 128);
        const float4* xs = (const float4*)(x + (size_t)s * 128);
#pragma unroll
        for (int q = 0; q < 4; q++) {
            *(float4*)&A[el][j * 16 + q * 4] = xd[j * 4 + q];
            *(float4*)&A[el][128 + j * 16 + q * 4] = xs[j * 4 + q];
        }
    }
    __syncthreads();

    // ---- GEMM1: A[32x257] @ W1[257x256] + b1, swish -> M ----
    {
        const int c4 = (tid & 63) * 4;   // column quad (coalesced W loads in-wave)
        const int eg = (tid >> 6) * 8;   // 8 edges per thread (LDS broadcast in-wave)
        float acc[8][4];
#pragma unroll
        for (int e = 0; e < 8; e++)
#pragma unroll
            for (int j = 0; j < 4; j++) acc[e][j] = 0.f;

        for (int k = 0; k < 256; k += 4) {
            float4 w0 = *(const float4*)(W1 + (size_t)(k + 0) * 256 + c4);
            float4 w1v = *(const float4*)(W1 + (size_t)(k + 1) * 256 + c4);
            float4 w2v = *(const float4*)(W1 + (size_t)(k + 2) * 256 + c4);
            float4 w3v = *(const float4*)(W1 + (size_t)(k + 3) * 256 + c4);
#pragma unroll
            for (int e = 0; e < 8; e++) {
                float4 av = *(const float4*)&A[eg + e][k];
                fma4(acc[e], av.x, w0);
                fma4(acc[e], av.y, w1v);
                fma4(acc[e], av.z, w2v);
                fma4(acc[e], av.w, w3v);
            }
        }
        // k = 256 tail (the d2 column)
        {
            float4 wt = *(const float4*)(W1 + (size_t)256 * 256 + c4);
#pragma unroll
            for (int e = 0; e < 8; e++) {
                float a = A[eg + e][256];
                fma4(acc[e], a, wt);
            }
        }
        float4 bb = *(const float4*)(b1 + c4);
#pragma unroll
        for (int e = 0; e < 8; e++) {
            float4 mv;
            mv.x = swish_f(acc[e][0] + bb.x);
            mv.y = swish_f(acc[e][1] + bb.y);
            mv.z = swish_f(acc[e][2] + bb.z);
            mv.w = swish_f(acc[e][3] + bb.w);
            *(float4*)&M[eg + e][c4] = mv;
        }
    }
    __syncthreads();

    // ---- GEMM2: M[32x256] @ W2[256x128] + b2, swish, atomic scatter ----
    {
        const int c4 = (tid & 31) * 4;   // column quad of 128
        const int eg = (tid >> 5) * 4;   // 4 edges per thread
        float acc[4][4];
#pragma unroll
        for (int e = 0; e < 4; e++)
#pragma unroll
            for (int j = 0; j < 4; j++) acc[e][j] = 0.f;

        for (int k = 0; k < 256; k += 4) {
            float4 w0 = *(const float4*)(W2 + (size_t)(k + 0) * 128 + c4);
            float4 w1v = *(const float4*)(W2 + (size_t)(k + 1) * 128 + c4);
            float4 w2v = *(const float4*)(W2 + (size_t)(k + 2) * 128 + c4);
            float4 w3v = *(const float4*)(W2 + (size_t)(k + 3) * 128 + c4);
#pragma unroll
            for (int e = 0; e < 4; e++) {
                float4 av = *(const float4*)&M[eg + e][k];
                fma4(acc[e], av.x, w0);
                fma4(acc[e], av.y, w1v);
                fma4(acc[e], av.z, w2v);
                fma4(acc[e], av.w, w3v);
            }
        }
        float4 bb = *(const float4*)(b2 + c4);
#pragma unroll
        for (int e = 0; e < 4; e++) {
            int dn = s_dst[eg + e];
            float* ap = agg + (size_t)dn * 128 + c4;
            atomicAdd(ap + 0, swish_f(acc[e][0] + bb.x));
            atomicAdd(ap + 1, swish_f(acc[e][1] + bb.y));
            atomicAdd(ap + 2, swish_f(acc[e][2] + bb.z));
            atomicAdd(ap + 3, swish_f(acc[e][3] + bb.w));
        }
    }
}

// Node update: h = swish(concat(x,agg) @ W1 + b1) @ W2 + b2 ; x += h
__global__ __launch_bounds__(256, 2) void node_mlp_kernel(
    float* __restrict__ x, const float* __restrict__ agg,
    const float* __restrict__ W1, const float* __restrict__ b1,
    const float* __restrict__ W2, const float* __restrict__ b2) {
    __shared__ float A[32][260];   // [node][256]: 0:128 x, 128:256 agg
    __shared__ float H[32][260];
    const int tid = threadIdx.x;
    const int n0 = blockIdx.x * 32;

    {
        int nl = tid >> 3;
        int j = tid & 7;
        int gn = n0 + nl;
        if (gn < N_NODES) {
            const float4* xp = (const float4*)(x + (size_t)gn * 128);
            const float4* ap = (const float4*)(agg + (size_t)gn * 128);
#pragma unroll
            for (int q = 0; q < 4; q++) {
                *(float4*)&A[nl][j * 16 + q * 4] = xp[j * 4 + q];
                *(float4*)&A[nl][128 + j * 16 + q * 4] = ap[j * 4 + q];
            }
        } else {
            float4 z4 = make_float4(0.f, 0.f, 0.f, 0.f);
#pragma unroll
            for (int q = 0; q < 4; q++) {
                *(float4*)&A[nl][j * 16 + q * 4] = z4;
                *(float4*)&A[nl][128 + j * 16 + q * 4] = z4;
            }
        }
    }
    __syncthreads();

    // GEMM1: [32x256]@[256x256] + b1, swish -> H
    {
        const int c4 = (tid & 63) * 4;
        const int eg = (tid >> 6) * 8;
        float acc[8][4];
#pragma unroll
        for (int e = 0; e < 8; e++)
#pragma unroll
            for (int j = 0; j < 4; j++) acc[e][j] = 0.f;

        for (int k = 0; k < 256; k += 4) {
            float4 w0 = *(const float4*)(W1 + (size_t)(k + 0) * 256 + c4);
            float4 w1v = *(const float4*)(W1 + (size_t)(k + 1) * 256 + c4);
            float4 w2v = *(const float4*)(W1 + (size_t)(k + 2) * 256 + c4);
            float4 w3v = *(const float4*)(W1 + (size_t)(k + 3) * 256 + c4);
#pragma unroll
            for (int e = 0; e < 8; e++) {
                float4 av = *(const float4*)&A[eg + e][k];
                fma4(acc[e], av.x, w0);
                fma4(acc[e], av.y, w1v);
                fma4(acc[e], av.z, w2v);
                fma4(acc[e], av.w, w3v);
            }
        }
        float4 bb = *(const float4*)(b1 + c4);
#pragma unroll
        for (int e = 0; e < 8; e++) {
            float4 mv;
            mv.x = swish_f(acc[e][0] + bb.x);
            mv.y = swish_f(acc[e][1] + bb.y);
            mv.z = swish_f(acc[e][2] + bb.z);
            mv.w = swish_f(acc[e][3] + bb.w);
            *(float4*)&H[eg + e][c4] = mv;
        }
    }
    __syncthreads();

    // GEMM2: H[32x256]@[256x128] + b2 ; x += (residual, no activation)
    {
        const int c4 = (tid & 31) * 4;
        const int eg = (tid >> 5) * 4;
        float acc[4][4];
#pragma unroll
        for (int e = 0; e < 4; e++)
#pragma unroll
            for (int j = 0; j < 4; j++) acc[e][j] = 0.f;

        for (int k = 0; k < 256; k += 4) {
            float4 w0 = *(const float4*)(W2 + (size_t)(k + 0) * 128 + c4);
            float4 w1v = *(const float4*)(W2 + (size_t)(k + 1) * 128 + c4);
            float4 w2v = *(const float4*)(W2 + (size_t)(k + 2) * 128 + c4);
            float4 w3v = *(const float4*)(W2 + (size_t)(k + 3) * 128 + c4);
#pragma unroll
            for (int e = 0; e < 4; e++) {
                float4 av = *(const float4*)&H[eg + e][k];
                fma4(acc[e], av.x, w0);
                fma4(acc[e], av.y, w1v);
                fma4(acc[e], av.z, w2v);
                fma4(acc[e], av.w, w3v);
            }
        }
        float4 bb = *(const float4*)(b2 + c4);
#pragma unroll
        for (int e = 0; e < 4; e++) {
            int gn = n0 + eg + e;
            if (gn < N_NODES) {
                float4 ov;
                ov.x = A[eg + e][c4 + 0] + acc[e][0] + bb.x;
                ov.y = A[eg + e][c4 + 1] + acc[e][1] + bb.y;
                ov.z = A[eg + e][c4 + 2] + acc[e][2] + bb.z;
                ov.w = A[eg + e][c4 + 3] + acc[e][3] + bb.w;
                *(float4*)(x + (size_t)gn * 128 + c4) = ov;
            }
        }
    }
}

// Output head: per node h = swish(x @ ow1 + ob1); s = h @ ow2 + ob2; atomicAdd(out[batch[n]], s)
__global__ __launch_bounds__(256, 4) void out_kernel(
    const float* __restrict__ x, const float* __restrict__ w1, const float* __restrict__ b1,
    const float* __restrict__ w2, const float* __restrict__ b2,
    const int* __restrict__ batch, float* __restrict__ out) {
    __shared__ float xr[4][128];
    __shared__ float red[4][4];  // [wave][node]
    const int tid = threadIdx.x;
    const int n0 = blockIdx.x * 4;

    {
        int i1 = tid;
        int nl1 = i1 >> 7, c1 = i1 & 127;
        int g1 = n0 + nl1;
        xr[nl1][c1] = (g1 < N_NODES) ? x[(size_t)g1 * 128 + c1] : 0.f;
        int i2 = tid + 256;
        int nl2 = i2 >> 7, c2 = i2 & 127;
        int g2 = n0 + nl2;
        xr[nl2][c2] = (g2 < N_NODES) ? x[(size_t)g2 * 128 + c2] : 0.f;
    }
    __syncthreads();

    float acc[4] = {0.f, 0.f, 0.f, 0.f};
    for (int k = 0; k < 128; k += 4) {
#pragma unroll
        for (int kk = 0; kk < 4; kk++) {
            float w = w1[(size_t)(k + kk) * 256 + tid];
            acc[0] += xr[0][k + kk] * w;
            acc[1] += xr[1][k + kk] * w;
            acc[2] += xr[2][k + kk] * w;
            acc[3] += xr[3][k + kk] * w;
        }
    }
    float bb = b1[tid];
    float wc = w2[tid];
    float val[4];
#pragma unroll
    for (int nn = 0; nn < 4; nn++) val[nn] = swish_f(acc[nn] + bb) * wc;

#pragma unroll
    for (int off = 32; off > 0; off >>= 1) {
#pragma unroll
        for (int nn = 0; nn < 4; nn++) val[nn] += __shfl_down(val[nn], off, 64);
    }
    int wid = tid >> 6;
    if ((tid & 63) == 0) {
#pragma unroll
        for (int nn = 0; nn < 4; nn++) red[wid][nn] = val[nn];
    }
    __syncthreads();
    if (tid < 4) {
        int gn = n0 + tid;
        if (gn < N_NODES) {
            float t = red[0][tid] + red[1][tid] + red[2][tid] + red[3][tid] + b2[0];
            atomicAdd(&out[batch[gn]], t);
        }
    }
}

extern "C" void kernel_launch(void* const* d_in, const int* in_sizes, int n_in,
                              void* d_out, int out_size, void* d_ws, size_t ws_size,
                              hipStream_t stream) {
    const float* positions = (const float*)d_in[0];
    const float* edge_shift = (const float*)d_in[1];
    const float* lattice = (const float*)d_in[2];
    const int* atomic_numbers = (const int*)d_in[3];
    const int* edge_index = (const int*)d_in[4];
    const int* batch = (const int*)d_in[5];
    const float* embed_w = (const float*)d_in[6];
    const float* edge_w1 = (const float*)d_in[7];
    const float* edge_b1 = (const float*)d_in[8];
    const float* edge_w2 = (const float*)d_in[9];
    const float* edge_b2 = (const float*)d_in[10];
    const float* node_w1 = (const float*)d_in[11];
    const float* node_b1 = (const float*)d_in[12];
    const float* node_w2 = (const float*)d_in[13];
    const float* node_b2 = (const float*)d_in[14];
    const float* out_w1 = (const float*)d_in[15];
    const float* out_b1 = (const float*)d_in[16];
    const float* out_w2 = (const float*)d_in[17];
    const float* out_b2 = (const float*)d_in[18];

    float* ws = (float*)d_ws;
    float* x = ws;                              // N*128
    float* agg = x + (size_t)N_NODES * 128;     // N*128
    float* d2 = agg + (size_t)N_NODES * 128;    // E

    (void)hipMemsetAsync(d_out, 0, (size_t)out_size * sizeof(float), stream);
    prep_kernel<<<(N_EDGES + 255) / 256, 256, 0, stream>>>(positions, edge_shift, lattice,
                                                           edge_index, batch, d2);
    embed_kernel<<<(N_NODES * 128) / 256, 256, 0, stream>>>(embed_w, atomic_numbers, x);

    for (int l = 0; l < N_LAYERS; l++) {
        (void)hipMemsetAsync(agg, 0, (size_t)N_NODES * 128 * sizeof(float), stream);
        edge_mlp_kernel<<<N_EDGES / 32, 256, 0, stream>>>(
            x, d2, edge_index,
            edge_w1 + (size_t)l * 257 * 256, edge_b1 + (size_t)l * 256,
            edge_w2 + (size_t)l * 256 * 128, edge_b2 + (size_t)l * 128, agg);
        node_mlp_kernel<<<(N_NODES + 31) / 32, 256, 0, stream>>>(
            x, agg,
            node_w1 + (size_t)l * 256 * 256, node_b1 + (size_t)l * 256,
            node_w2 + (size_t)l * 256 * 128, node_b2 + (size_t)l * 128);
    }
    out_kernel<<<N_NODES / 4, 256, 0, stream>>>(x, out_w1, out_b1, out_w2, out_b2, batch,
                                                (float*)d_out);
}

// Round 3
// 4865.880 us; speedup vs baseline: 1.7266x; 1.7266x over previous
//
#include <hip/hip_runtime.h>
#include <hip/hip_bf16.h>

#define N_NODES 50000
#define N_EDGES 800000
#define N_GRAPHS 32
#define NODE_DIM 128
#define HIDDEN 256
#define N_LAYERS 3

typedef __attribute__((ext_vector_type(8))) short bh8;   // 8 bf16 (4 VGPRs)
typedef __attribute__((ext_vector_type(4))) short bh4;   // 4 bf16 (8B)
typedef __attribute__((ext_vector_type(4))) float f32x4; // MFMA acc

#define AP 296  // edge A-tile pitch (bf16): 592B = 148 words, 148%32=20 -> 2-way (free)
#define MP 264  // M/H tile pitch (bf16): 528B = 132 words, 132%32=4 -> 2-way (free)

__device__ __forceinline__ float swish_f(float v) { return v / (1.0f + __expf(-v)); }

__device__ __forceinline__ short f2bf(float f) {
    union { float f; unsigned u; } v;
    v.f = f;
    unsigned r = v.u + 0x7FFF + ((v.u >> 16) & 1);  // RNE
    return (short)(r >> 16);
}

// d2[e] = |pos[dst] - pos[src] + shift @ lattice[batch[src]]|^2
__global__ void prep_kernel(const float* __restrict__ pos, const float* __restrict__ shift,
                            const float* __restrict__ lattice, const int* __restrict__ eidx,
                            const int* __restrict__ batch, float* __restrict__ d2) {
    int e = blockIdx.x * blockDim.x + threadIdx.x;
    if (e >= N_EDGES) return;
    int s = eidx[e];
    int d = eidx[N_EDGES + e];
    int b = batch[s];
    const float* lat = lattice + b * 9;
    float s0 = shift[e * 3 + 0], s1 = shift[e * 3 + 1], s2 = shift[e * 3 + 2];
    float acc = 0.f;
#pragma unroll
    for (int j = 0; j < 3; j++) {
        float v = pos[d * 3 + j] - pos[s * 3 + j] + s0 * lat[j] + s1 * lat[3 + j] + s2 * lat[6 + j];
        acc += v * v;
    }
    d2[e] = acc;
}

// x[n][c] = embed[z[n]][c]; also bf16 mirror
__global__ void embed_kernel(const float* __restrict__ emb, const int* __restrict__ z,
                             float* __restrict__ x, short* __restrict__ xb) {
    int i = blockIdx.x * blockDim.x + threadIdx.x;  // over N*128
    int n = i >> 7, c = i & 127;
    float v = emb[z[n] * 128 + c];
    x[i] = v;
    xb[i] = f2bf(v);
}

// out[l][h][k] = bf16(in[l][k][h]) for k<K_in else 0.  (transpose + pad + cvt)
__global__ void cvt_wT_kernel(const float* __restrict__ in, short* __restrict__ out,
                              int K_in, int H, int K_pad, int total) {
    int i = blockIdx.x * blockDim.x + threadIdx.x;
    if (i >= total) return;
    int k = i % K_pad;
    int t = i / K_pad;
    int h = t % H;
    int l = t / H;
    out[i] = (k < K_in) ? f2bf(in[((size_t)l * K_in + k) * H + h]) : (short)0;
}

// ---------------- Edge MLP (MFMA) ----------------
// GEMM1: D1[h][e] = sum_k W1T[h][k] * A[e][k]   (K=288 padded, h=256)
// GEMM2: D2[c][e] = sum_h W2T[c][h] * M[e][h]   (K=256, c=128), atomic scatter by dst.
__global__ __launch_bounds__(256, 2) void edge_mlp_mfma(
    const short* __restrict__ xb, const float* __restrict__ d2,
    const int* __restrict__ eidx,
    const short* __restrict__ W1T,  // [256][288] bf16
    const float* __restrict__ b1,
    const short* __restrict__ W2T,  // [128][256] bf16
    const float* __restrict__ b2,
    float* __restrict__ agg) {
    __shared__ short A[64 * AP];
    __shared__ short M[64 * MP];
    __shared__ int s_dst[64];
    const int tid = threadIdx.x;
    const int e0 = blockIdx.x * 64;
    const int wv = tid >> 6;   // wave 0..3
    const int ln = tid & 63;
    const int lr = ln & 15;    // tile row/col lane component
    const int lq = ln >> 4;    // quad

    // ---- stage A: [e][0:128]=x[dst], [128:256]=x[src], [256]=d2, [257:288]=0 ----
    {
        int el = tid >> 2, p = tid & 3;  // 4 threads/edge, each 4 int4-chunks per half
        int ge = e0 + el;
        int s = eidx[ge];
        int d = eidx[N_EDGES + ge];
        const int4* xd = (const int4*)(xb + (size_t)d * 128);
        const int4* xs = (const int4*)(xb + (size_t)s * 128);
#pragma unroll
        for (int q = 0; q < 4; q++) {
            int c = p * 4 + q;  // chunk 0..15 (8 bf16 each)
            *(int4*)(A + el * AP + c * 8) = xd[c];
            *(int4*)(A + el * AP + 128 + c * 8) = xs[c];
        }
        if (p == 0) {
            s_dst[el] = d;
            union { int4 v; short s[8]; } z;
            z.v = make_int4(0, 0, 0, 0);
            int4 z4 = make_int4(0, 0, 0, 0);
            short* t = A + el * AP + 256;
            *(int4*)(t + 8) = z4;
            *(int4*)(t + 16) = z4;
            *(int4*)(t + 24) = z4;
            z.s[0] = f2bf(d2[ge]);
            *(int4*)t = z.v;
        }
    }
    __syncthreads();

    // ---- GEMM1 + swish -> M (bf16, row-major [e][h]) ----
    {
        f32x4 acc[4][4];  // [mt: h-tile][nt: e-tile]
#pragma unroll
        for (int a = 0; a < 4; a++)
#pragma unroll
            for (int b = 0; b < 4; b++) acc[a][b] = (f32x4)(0.f);

        const short* a_base = W1T + (size_t)(wv * 64 + lr) * 288 + lq * 8;
        for (int ks = 0; ks < 288; ks += 32) {
            bh8 af[4], bf[4];
#pragma unroll
            for (int mt = 0; mt < 4; mt++) af[mt] = *(const bh8*)(a_base + mt * 16 * 288 + ks);
#pragma unroll
            for (int nt = 0; nt < 4; nt++)
                bf[nt] = *(const bh8*)(A + (nt * 16 + lr) * AP + ks + lq * 8);
#pragma unroll
            for (int mt = 0; mt < 4; mt++)
#pragma unroll
                for (int nt = 0; nt < 4; nt++)
                    acc[mt][nt] = __builtin_amdgcn_mfma_f32_16x16x32_bf16(af[mt], bf[nt],
                                                                          acc[mt][nt], 0, 0, 0);
        }
#pragma unroll
        for (int mt = 0; mt < 4; mt++) {
            int h0 = wv * 64 + mt * 16 + lq * 4;
            float4 bb = *(const float4*)(b1 + h0);
#pragma unroll
            for (int nt = 0; nt < 4; nt++) {
                int e = nt * 16 + lr;
                bh4 pk;
                pk[0] = f2bf(swish_f(acc[mt][nt][0] + bb.x));
                pk[1] = f2bf(swish_f(acc[mt][nt][1] + bb.y));
                pk[2] = f2bf(swish_f(acc[mt][nt][2] + bb.z));
                pk[3] = f2bf(swish_f(acc[mt][nt][3] + bb.w));
                *(bh4*)(M + e * MP + h0) = pk;
            }
        }
    }
    __syncthreads();

    // ---- GEMM2 + swish + atomic scatter ----
    {
        f32x4 acc[2][4];  // [mt2: c-tile][nt: e-tile]
#pragma unroll
        for (int a = 0; a < 2; a++)
#pragma unroll
            for (int b = 0; b < 4; b++) acc[a][b] = (f32x4)(0.f);

        const short* a_base = W2T + (size_t)(wv * 32 + lr) * 256 + lq * 8;
        for (int ks = 0; ks < 256; ks += 32) {
            bh8 af[2], bf[4];
#pragma unroll
            for (int mt = 0; mt < 2; mt++) af[mt] = *(const bh8*)(a_base + mt * 16 * 256 + ks);
#pragma unroll
            for (int nt = 0; nt < 4; nt++)
                bf[nt] = *(const bh8*)(M + (nt * 16 + lr) * MP + ks + lq * 8);
#pragma unroll
            for (int mt = 0; mt < 2; mt++)
#pragma unroll
                for (int nt = 0; nt < 4; nt++)
                    acc[mt][nt] = __builtin_amdgcn_mfma_f32_16x16x32_bf16(af[mt], bf[nt],
                                                                          acc[mt][nt], 0, 0, 0);
        }
#pragma unroll
        for (int mt = 0; mt < 2; mt++) {
            int c0 = wv * 32 + mt * 16 + lq * 4;
            float4 bb = *(const float4*)(b2 + c0);
#pragma unroll
            for (int nt = 0; nt < 4; nt++) {
                int e = nt * 16 + lr;
                int dn = s_dst[e];
                float* ap = agg + (size_t)dn * 128 + c0;
                atomicAdd(ap + 0, swish_f(acc[mt][nt][0] + bb.x));
                atomicAdd(ap + 1, swish_f(acc[mt][nt][1] + bb.y));
                atomicAdd(ap + 2, swish_f(acc[mt][nt][2] + bb.z));
                atomicAdd(ap + 3, swish_f(acc[mt][nt][3] + bb.w));
            }
        }
    }
}

// ---------------- Node MLP (MFMA) ----------------
// A = concat(x, agg) [64 nodes][256] bf16; GEMM1 -> H (swish); GEMM2 + residual -> x, xb.
__global__ __launch_bounds__(256, 2) void node_mlp_mfma(
    float* __restrict__ x, short* __restrict__ xb, const float* __restrict__ agg,
    const short* __restrict__ W1T,  // [256][256] bf16
    const float* __restrict__ b1,
    const short* __restrict__ W2T,  // [128][256] bf16
    const float* __restrict__ b2) {
    __shared__ short A[64 * MP];
    __shared__ short H[64 * MP];
    const int tid = threadIdx.x;
    const int n0 = blockIdx.x * 64;
    const int wv = tid >> 6;
    const int ln = tid & 63;
    const int lr = ln & 15;
    const int lq = ln >> 4;

    // ---- stage: x (bf16 copy) + agg (fp32 -> bf16) ----
    {
        int row = tid >> 2, p = tid & 3;
        int gn = n0 + row;
        if (gn < N_NODES) {
            const int4* xp = (const int4*)(xb + (size_t)gn * 128);
#pragma unroll
            for (int q = 0; q < 4; q++) {
                int c = p * 4 + q;
                *(int4*)(A + row * MP + c * 8) = xp[c];
            }
            const float4* ap = (const float4*)(agg + (size_t)gn * 128);
#pragma unroll
            for (int q = 0; q < 4; q++) {
                float4 f0 = ap[p * 8 + q * 2];
                float4 f1 = ap[p * 8 + q * 2 + 1];
                bh8 s;
                s[0] = f2bf(f0.x); s[1] = f2bf(f0.y); s[2] = f2bf(f0.z); s[3] = f2bf(f0.w);
                s[4] = f2bf(f1.x); s[5] = f2bf(f1.y); s[6] = f2bf(f1.z); s[7] = f2bf(f1.w);
                *(bh8*)(A + row * MP + 128 + p * 32 + q * 8) = s;
            }
        } else {
            int4 z4 = make_int4(0, 0, 0, 0);
#pragma unroll
            for (int q = 0; q < 8; q++) *(int4*)(A + row * MP + (p * 8 + q) * 8) = z4;
        }
    }
    __syncthreads();

    // ---- GEMM1 + swish -> H ----
    {
        f32x4 acc[4][4];
#pragma unroll
        for (int a = 0; a < 4; a++)
#pragma unroll
            for (int b = 0; b < 4; b++) acc[a][b] = (f32x4)(0.f);

        const short* a_base = W1T + (size_t)(wv * 64 + lr) * 256 + lq * 8;
        for (int ks = 0; ks < 256; ks += 32) {
            bh8 af[4], bf[4];
#pragma unroll
            for (int mt = 0; mt < 4; mt++) af[mt] = *(const bh8*)(a_base + mt * 16 * 256 + ks);
#pragma unroll
            for (int nt = 0; nt < 4; nt++)
                bf[nt] = *(const bh8*)(A + (nt * 16 + lr) * MP + ks + lq * 8);
#pragma unroll
            for (int mt = 0; mt < 4; mt++)
#pragma unroll
                for (int nt = 0; nt < 4; nt++)
                    acc[mt][nt] = __builtin_amdgcn_mfma_f32_16x16x32_bf16(af[mt], bf[nt],
                                                                          acc[mt][nt], 0, 0, 0);
        }
#pragma unroll
        for (int mt = 0; mt < 4; mt++) {
            int h0 = wv * 64 + mt * 16 + lq * 4;
            float4 bb = *(const float4*)(b1 + h0);
#pragma unroll
            for (int nt = 0; nt < 4; nt++) {
                int e = nt * 16 + lr;
                bh4 pk;
                pk[0] = f2bf(swish_f(acc[mt][nt][0] + bb.x));
                pk[1] = f2bf(swish_f(acc[mt][nt][1] + bb.y));
                pk[2] = f2bf(swish_f(acc[mt][nt][2] + bb.z));
                pk[3] = f2bf(swish_f(acc[mt][nt][3] + bb.w));
                *(bh4*)(H + e * MP + h0) = pk;
            }
        }
    }
    __syncthreads();

    // ---- GEMM2 + residual -> x, xb ----
    {
        f32x4 acc[2][4];
#pragma unroll
        for (int a = 0; a < 2; a++)
#pragma unroll
            for (int b = 0; b < 4; b++) acc[a][b] = (f32x4)(0.f);

        const short* a_base = W2T + (size_t)(wv * 32 + lr) * 256 + lq * 8;
        for (int ks = 0; ks < 256; ks += 32) {
            bh8 af[2], bf[4];
#pragma unroll
            for (int mt = 0; mt < 2; mt++) af[mt] = *(const bh8*)(a_base + mt * 16 * 256 + ks);
#pragma unroll
            for (int nt = 0; nt < 4; nt++)
                bf[nt] = *(const bh8*)(H + (nt * 16 + lr) * MP + ks + lq * 8);
#pragma unroll
            for (int mt = 0; mt < 2; mt++)
#pragma unroll
                for (int nt = 0; nt < 4; nt++)
                    acc[mt][nt] = __builtin_amdgcn_mfma_f32_16x16x32_bf16(af[mt], bf[nt],
                                                                          acc[mt][nt], 0, 0, 0);
        }
#pragma unroll
        for (int mt = 0; mt < 2; mt++) {
            int c0 = wv * 32 + mt * 16 + lq * 4;
            float4 bb = *(const float4*)(b2 + c0);
#pragma unroll
            for (int nt = 0; nt < 4; nt++) {
                int nl = nt * 16 + lr;
                int gn = n0 + nl;
                if (gn < N_NODES) {
                    float4 xv = *(const float4*)(x + (size_t)gn * 128 + c0);
                    float4 nv;
                    nv.x = xv.x + acc[mt][nt][0] + bb.x;
                    nv.y = xv.y + acc[mt][nt][1] + bb.y;
                    nv.z = xv.z + acc[mt][nt][2] + bb.z;
                    nv.w = xv.w + acc[mt][nt][3] + bb.w;
                    *(float4*)(x + (size_t)gn * 128 + c0) = nv;
                    bh4 pk;
                    pk[0] = f2bf(nv.x); pk[1] = f2bf(nv.y); pk[2] = f2bf(nv.z); pk[3] = f2bf(nv.w);
                    *(bh4*)(xb + (size_t)gn * 128 + c0) = pk;
                }
            }
        }
    }
}

// Output head (fp32): per node h = swish(x @ ow1 + ob1); s = h @ ow2 + ob2; atomicAdd per graph
__global__ __launch_bounds__(256, 4) void out_kernel(
    const float* __restrict__ x, const float* __restrict__ w1, const float* __restrict__ b1,
    const float* __restrict__ w2, const float* __restrict__ b2,
    const int* __restrict__ batch, float* __restrict__ out) {
    __shared__ float xr[4][128];
    __shared__ float red[4][4];
    const int tid = threadIdx.x;
    const int n0 = blockIdx.x * 4;

    {
        int i1 = tid;
        int nl1 = i1 >> 7, c1 = i1 & 127;
        int g1 = n0 + nl1;
        xr[nl1][c1] = (g1 < N_NODES) ? x[(size_t)g1 * 128 + c1] : 0.f;
        int i2 = tid + 256;
        int nl2 = i2 >> 7, c2 = i2 & 127;
        int g2 = n0 + nl2;
        xr[nl2][c2] = (g2 < N_NODES) ? x[(size_t)g2 * 128 + c2] : 0.f;
    }
    __syncthreads();

    float acc[4] = {0.f, 0.f, 0.f, 0.f};
    for (int k = 0; k < 128; k += 4) {
#pragma unroll
        for (int kk = 0; kk < 4; kk++) {
            float w = w1[(size_t)(k + kk) * 256 + tid];
            acc[0] += xr[0][k + kk] * w;
            acc[1] += xr[1][k + kk] * w;
            acc[2] += xr[2][k + kk] * w;
            acc[3] += xr[3][k + kk] * w;
        }
    }
    float bb = b1[tid];
    float wc = w2[tid];
    float val[4];
#pragma unroll
    for (int nn = 0; nn < 4; nn++) val[nn] = swish_f(acc[nn] + bb) * wc;

#pragma unroll
    for (int off = 32; off > 0; off >>= 1) {
#pragma unroll
        for (int nn = 0; nn < 4; nn++) val[nn] += __shfl_down(val[nn], off, 64);
    }
    int wid = tid >> 6;
    if ((tid & 63) == 0) {
#pragma unroll
        for (int nn = 0; nn < 4; nn++) red[wid][nn] = val[nn];
    }
    __syncthreads();
    if (tid < 4) {
        int gn = n0 + tid;
        if (gn < N_NODES) {
            float t = red[0][tid] + red[1][tid] + red[2][tid] + red[3][tid] + b2[0];
            atomicAdd(&out[batch[gn]], t);
        }
    }
}

extern "C" void kernel_launch(void* const* d_in, const int* in_sizes, int n_in,
                              void* d_out, int out_size, void* d_ws, size_t ws_size,
                              hipStream_t stream) {
    const float* positions = (const float*)d_in[0];
    const float* edge_shift = (const float*)d_in[1];
    const float* lattice = (const float*)d_in[2];
    const int* atomic_numbers = (const int*)d_in[3];
    const int* edge_index = (const int*)d_in[4];
    const int* batch = (const int*)d_in[5];
    const float* embed_w = (const float*)d_in[6];
    const float* edge_w1 = (const float*)d_in[7];
    const float* edge_b1 = (const float*)d_in[8];
    const float* edge_w2 = (const float*)d_in[9];
    const float* edge_b2 = (const float*)d_in[10];
    const float* node_w1 = (const float*)d_in[11];
    const float* node_b1 = (const float*)d_in[12];
    const float* node_w2 = (const float*)d_in[13];
    const float* node_b2 = (const float*)d_in[14];
    const float* out_w1 = (const float*)d_in[15];
    const float* out_b1 = (const float*)d_in[16];
    const float* out_w2 = (const float*)d_in[17];
    const float* out_b2 = (const float*)d_in[18];

    // workspace layout
    float* ws = (float*)d_ws;
    float* x = ws;                               // N*128 f32
    float* agg = x + (size_t)N_NODES * 128;      // N*128 f32
    float* d2 = agg + (size_t)N_NODES * 128;     // E f32
    short* xb = (short*)(d2 + N_EDGES);          // N*128 bf16
    short* eW1T = xb + (size_t)N_NODES * 128;    // 3*256*288
    short* eW2T = eW1T + 3 * 256 * 288;          // 3*128*256
    short* nW1T = eW2T + 3 * 128 * 256;          // 3*256*256
    short* nW2T = nW1T + 3 * 256 * 256;          // 3*128*256

    (void)hipMemsetAsync(d_out, 0, (size_t)out_size * sizeof(float), stream);

    // weight transpose+cvt (tiny)
    {
        int t1 = 3 * 256 * 288;
        cvt_wT_kernel<<<(t1 + 255) / 256, 256, 0, stream>>>(edge_w1, eW1T, 257, 256, 288, t1);
        int t2 = 3 * 128 * 256;
        cvt_wT_kernel<<<(t2 + 255) / 256, 256, 0, stream>>>(edge_w2, eW2T, 256, 128, 256, t2);
        int t3 = 3 * 256 * 256;
        cvt_wT_kernel<<<(t3 + 255) / 256, 256, 0, stream>>>(node_w1, nW1T, 256, 256, 256, t3);
        cvt_wT_kernel<<<(t2 + 255) / 256, 256, 0, stream>>>(node_w2, nW2T, 256, 128, 256, t2);
    }

    prep_kernel<<<(N_EDGES + 255) / 256, 256, 0, stream>>>(positions, edge_shift, lattice,
                                                           edge_index, batch, d2);
    embed_kernel<<<(N_NODES * 128) / 256, 256, 0, stream>>>(embed_w, atomic_numbers, x, xb);

    for (int l = 0; l < N_LAYERS; l++) {
        (void)hipMemsetAsync(agg, 0, (size_t)N_NODES * 128 * sizeof(float), stream);
        edge_mlp_mfma<<<N_EDGES / 64, 256, 0, stream>>>(
            xb, d2, edge_index,
            eW1T + (size_t)l * 256 * 288, edge_b1 + (size_t)l * 256,
            eW2T + (size_t)l * 128 * 256, edge_b2 + (size_t)l * 128, agg);
        node_mlp_mfma<<<(N_NODES + 63) / 64, 256, 0, stream>>>(
            x, xb, agg,
            nW1T + (size_t)l * 256 * 256, node_b1 + (size_t)l * 256,
            nW2T + (size_t)l * 128 * 256, node_b2 + (size_t)l * 128);
    }
    out_kernel<<<N_NODES / 4, 256, 0, stream>>>(x, out_w1, out_b1, out_w2, out_b2, batch,
                                                (float*)d_out);
}

// Round 4
// 1982.770 us; speedup vs baseline: 4.2373x; 2.4541x over previous
//
#include <hip/hip_runtime.h>
#include <hip/hip_bf16.h>

#define N_NODES 50000
#define N_EDGES 800000
#define N_GRAPHS 32
#define NODE_DIM 128
#define HIDDEN 256
#define N_LAYERS 3

typedef __attribute__((ext_vector_type(8))) short bh8;   // 8 bf16 (4 VGPRs)
typedef __attribute__((ext_vector_type(4))) short bh4;   // 4 bf16 (8B)
typedef __attribute__((ext_vector_type(4))) float f32x4; // MFMA acc

#define AP 296  // edge A-tile pitch (bf16)
#define MP 264  // M/H tile pitch (bf16)
#define SP 132  // S tile pitch (fp32) — 528B, 16B-aligned rows, (4e+c)%32 conflict-free reads
#define SCAN_BS 512

__device__ __forceinline__ float swish_f(float v) { return v / (1.0f + __expf(-v)); }

__device__ __forceinline__ short f2bf(float f) {
    union { float f; unsigned u; } v;
    v.f = f;
    unsigned r = v.u + 0x7FFF + ((v.u >> 16) & 1);  // RNE
    return (short)(r >> 16);
}

// d2[e] = |pos[dst] - pos[src] + shift @ lattice[batch[src]]|^2
__global__ void prep_kernel(const float* __restrict__ pos, const float* __restrict__ shift,
                            const float* __restrict__ lattice, const int* __restrict__ eidx,
                            const int* __restrict__ batch, float* __restrict__ d2) {
    int e = blockIdx.x * blockDim.x + threadIdx.x;
    if (e >= N_EDGES) return;
    int s = eidx[e];
    int d = eidx[N_EDGES + e];
    int b = batch[s];
    const float* lat = lattice + b * 9;
    float s0 = shift[e * 3 + 0], s1 = shift[e * 3 + 1], s2 = shift[e * 3 + 2];
    float acc = 0.f;
#pragma unroll
    for (int j = 0; j < 3; j++) {
        float v = pos[d * 3 + j] - pos[s * 3 + j] + s0 * lat[j] + s1 * lat[3 + j] + s2 * lat[6 + j];
        acc += v * v;
    }
    d2[e] = acc;
}

// x[n][c] = embed[z[n]][c]; also bf16 mirror
__global__ void embed_kernel(const float* __restrict__ emb, const int* __restrict__ z,
                             float* __restrict__ x, short* __restrict__ xb) {
    int i = blockIdx.x * blockDim.x + threadIdx.x;
    int n = i >> 7, c = i & 127;
    float v = emb[z[n] * 128 + c];
    x[i] = v;
    xb[i] = f2bf(v);
}

// out[l][h][k] = bf16(in[l][k][h]) for k<K_in else 0
__global__ void cvt_wT_kernel(const float* __restrict__ in, short* __restrict__ out,
                              int K_in, int H, int K_pad, int total) {
    int i = blockIdx.x * blockDim.x + threadIdx.x;
    if (i >= total) return;
    int k = i % K_pad;
    int t = i / K_pad;
    int h = t % H;
    int l = t / H;
    out[i] = (k < K_in) ? f2bf(in[((size_t)l * K_in + k) * H + h]) : (short)0;
}

// ---- CSR counting-sort build ----
__global__ void hist_kernel(const int* __restrict__ eidx, int* __restrict__ deg) {
    int e = blockIdx.x * blockDim.x + threadIdx.x;
    if (e >= N_EDGES) return;
    atomicAdd(&deg[eidx[N_EDGES + e]], 1);
}

__global__ void scan1_kernel(const int* __restrict__ deg, int* __restrict__ sc,
                             int* __restrict__ bsum, int n) {
    __shared__ int s[SCAN_BS];
    int i = blockIdx.x * SCAN_BS + threadIdx.x;
    int v = (i < n) ? deg[i] : 0;
    s[threadIdx.x] = v;
    __syncthreads();
    for (int off = 1; off < SCAN_BS; off <<= 1) {
        int t = (threadIdx.x >= off) ? s[threadIdx.x - off] : 0;
        __syncthreads();
        s[threadIdx.x] += t;
        __syncthreads();
    }
    if (i < n) sc[i] = s[threadIdx.x];
    if (threadIdx.x == SCAN_BS - 1) bsum[blockIdx.x] = s[SCAN_BS - 1];
}

__global__ void scan2_kernel(int* __restrict__ bsum, int nb) {  // 1 block, 128 threads
    __shared__ int s[128];
    int v = (threadIdx.x < nb) ? bsum[threadIdx.x] : 0;
    s[threadIdx.x] = v;
    __syncthreads();
    for (int off = 1; off < 128; off <<= 1) {
        int t = (threadIdx.x >= off) ? s[threadIdx.x - off] : 0;
        __syncthreads();
        s[threadIdx.x] += t;
        __syncthreads();
    }
    if (threadIdx.x < nb) bsum[threadIdx.x] = s[threadIdx.x];
}

__global__ void scan3_kernel(const int* __restrict__ sc, const int* __restrict__ deg,
                             const int* __restrict__ bsum, int* __restrict__ rowptr,
                             int n, int total) {
    int i = blockIdx.x * SCAN_BS + threadIdx.x;
    if (i > n) return;
    if (i == n) { rowptr[n] = total; return; }
    int off = (blockIdx.x > 0) ? bsum[blockIdx.x - 1] : 0;
    rowptr[i] = sc[i] - deg[i] + off;
}

__global__ void fill_kernel(const int* __restrict__ eidx, const int* __restrict__ rowptr,
                            int* __restrict__ fillc, int* __restrict__ esorted) {
    int e = blockIdx.x * blockDim.x + threadIdx.x;
    if (e >= N_EDGES) return;
    int d = eidx[N_EDGES + e];
    int p = rowptr[d] + atomicAdd(&fillc[d], 1);
    esorted[p] = e;
}

// ---------------- Edge MLP (MFMA, dst-sorted, segmented-reduction scatter) ----------------
__global__ __launch_bounds__(256, 2) void edge_mlp_mfma(
    const short* __restrict__ xb, const float* __restrict__ d2,
    const int* __restrict__ eidx, const int* __restrict__ esorted,
    const short* __restrict__ W1T,  // [256][288] bf16
    const float* __restrict__ b1,
    const short* __restrict__ W2T,  // [128][256] bf16
    const float* __restrict__ b2,
    float* __restrict__ agg) {
    __shared__ short A[64 * AP];   // reused as S (fp32 [64][SP]) after GEMM1
    __shared__ short M[64 * MP];
    __shared__ int s_dst[64];
    float* S = (float*)A;
    const int tid = threadIdx.x;
    const int e0 = blockIdx.x * 64;
    const int wv = tid >> 6;
    const int ln = tid & 63;
    const int lr = ln & 15;
    const int lq = ln >> 4;

    // ---- stage A: sorted-edge gather ----
    {
        int el = tid >> 2, p = tid & 3;
        int ge = esorted[e0 + el];
        int s = eidx[ge];
        int d = eidx[N_EDGES + ge];
        const int4* xd = (const int4*)(xb + (size_t)d * 128);
        const int4* xs = (const int4*)(xb + (size_t)s * 128);
#pragma unroll
        for (int q = 0; q < 4; q++) {
            int c = p * 4 + q;
            *(int4*)(A + el * AP + c * 8) = xd[c];
            *(int4*)(A + el * AP + 128 + c * 8) = xs[c];
        }
        if (p == 0) {
            s_dst[el] = d;
            union { int4 v; short s[8]; } z;
            int4 z4 = make_int4(0, 0, 0, 0);
            z.v = z4;
            short* t = A + el * AP + 256;
            *(int4*)(t + 8) = z4;
            *(int4*)(t + 16) = z4;
            *(int4*)(t + 24) = z4;
            z.s[0] = f2bf(d2[ge]);
            *(int4*)t = z.v;
        }
    }
    __syncthreads();

    // ---- GEMM1 + swish -> M ----
    {
        f32x4 acc[4][4];
#pragma unroll
        for (int a = 0; a < 4; a++)
#pragma unroll
            for (int b = 0; b < 4; b++) acc[a][b] = (f32x4)(0.f);

        const short* a_base = W1T + (size_t)(wv * 64 + lr) * 288 + lq * 8;
        for (int ks = 0; ks < 288; ks += 32) {
            bh8 af[4], bf[4];
#pragma unroll
            for (int mt = 0; mt < 4; mt++) af[mt] = *(const bh8*)(a_base + mt * 16 * 288 + ks);
#pragma unroll
            for (int nt = 0; nt < 4; nt++)
                bf[nt] = *(const bh8*)(A + (nt * 16 + lr) * AP + ks + lq * 8);
#pragma unroll
            for (int mt = 0; mt < 4; mt++)
#pragma unroll
                for (int nt = 0; nt < 4; nt++)
                    acc[mt][nt] = __builtin_amdgcn_mfma_f32_16x16x32_bf16(af[mt], bf[nt],
                                                                          acc[mt][nt], 0, 0, 0);
        }
#pragma unroll
        for (int mt = 0; mt < 4; mt++) {
            int h0 = wv * 64 + mt * 16 + lq * 4;
            float4 bb = *(const float4*)(b1 + h0);
#pragma unroll
            for (int nt = 0; nt < 4; nt++) {
                int e = nt * 16 + lr;
                bh4 pk;
                pk[0] = f2bf(swish_f(acc[mt][nt][0] + bb.x));
                pk[1] = f2bf(swish_f(acc[mt][nt][1] + bb.y));
                pk[2] = f2bf(swish_f(acc[mt][nt][2] + bb.z));
                pk[3] = f2bf(swish_f(acc[mt][nt][3] + bb.w));
                *(bh4*)(M + e * MP + h0) = pk;
            }
        }
    }
    __syncthreads();   // GEMM1 A-reads done; A space free for S

    // ---- GEMM2 + swish -> S (fp32, LDS) ----
    {
        f32x4 acc[2][4];
#pragma unroll
        for (int a = 0; a < 2; a++)
#pragma unroll
            for (int b = 0; b < 4; b++) acc[a][b] = (f32x4)(0.f);

        const short* a_base = W2T + (size_t)(wv * 32 + lr) * 256 + lq * 8;
        for (int ks = 0; ks < 256; ks += 32) {
            bh8 af[2], bf[4];
#pragma unroll
            for (int mt = 0; mt < 2; mt++) af[mt] = *(const bh8*)(a_base + mt * 16 * 256 + ks);
#pragma unroll
            for (int nt = 0; nt < 4; nt++)
                bf[nt] = *(const bh8*)(M + (nt * 16 + lr) * MP + ks + lq * 8);
#pragma unroll
            for (int mt = 0; mt < 2; mt++)
#pragma unroll
                for (int nt = 0; nt < 4; nt++)
                    acc[mt][nt] = __builtin_amdgcn_mfma_f32_16x16x32_bf16(af[mt], bf[nt],
                                                                          acc[mt][nt], 0, 0, 0);
        }
#pragma unroll
        for (int mt = 0; mt < 2; mt++) {
            int c0 = wv * 32 + mt * 16 + lq * 4;
            float4 bb = *(const float4*)(b2 + c0);
#pragma unroll
            for (int nt = 0; nt < 4; nt++) {
                int e = nt * 16 + lr;
                float4 sv;
                sv.x = swish_f(acc[mt][nt][0] + bb.x);
                sv.y = swish_f(acc[mt][nt][1] + bb.y);
                sv.z = swish_f(acc[mt][nt][2] + bb.z);
                sv.w = swish_f(acc[mt][nt][3] + bb.w);
                *(float4*)&S[e * SP + c0] = sv;
            }
        }
    }
    __syncthreads();

    // ---- segmented reduction over sorted dst; one atomic per run ----
    {
        const int c = tid & 127;
        const int half = tid >> 7;
        const int eb = half * 32;
        int cur = s_dst[eb];
        float acc = S[eb * SP + c];
        for (int e2 = eb + 1; e2 < eb + 32; ++e2) {
            int dn = s_dst[e2];
            float v = S[e2 * SP + c];
            if (dn != cur) {
                atomicAdd(agg + (size_t)cur * 128 + c, acc);
                acc = v;
                cur = dn;
            } else {
                acc += v;
            }
        }
        atomicAdd(agg + (size_t)cur * 128 + c, acc);
    }
}

// ---------------- Node MLP (MFMA) ----------------
__global__ __launch_bounds__(256, 2) void node_mlp_mfma(
    float* __restrict__ x, short* __restrict__ xb, const float* __restrict__ agg,
    const short* __restrict__ W1T, const float* __restrict__ b1,
    const short* __restrict__ W2T, const float* __restrict__ b2) {
    __shared__ short A[64 * MP];
    __shared__ short H[64 * MP];
    const int tid = threadIdx.x;
    const int n0 = blockIdx.x * 64;
    const int wv = tid >> 6;
    const int ln = tid & 63;
    const int lr = ln & 15;
    const int lq = ln >> 4;

    {
        int row = tid >> 2, p = tid & 3;
        int gn = n0 + row;
        if (gn < N_NODES) {
            const int4* xp = (const int4*)(xb + (size_t)gn * 128);
#pragma unroll
            for (int q = 0; q < 4; q++) {
                int c = p * 4 + q;
                *(int4*)(A + row * MP + c * 8) = xp[c];
            }
            const float4* ap = (const float4*)(agg + (size_t)gn * 128);
#pragma unroll
            for (int q = 0; q < 4; q++) {
                float4 f0 = ap[p * 8 + q * 2];
                float4 f1 = ap[p * 8 + q * 2 + 1];
                bh8 s;
                s[0] = f2bf(f0.x); s[1] = f2bf(f0.y); s[2] = f2bf(f0.z); s[3] = f2bf(f0.w);
                s[4] = f2bf(f1.x); s[5] = f2bf(f1.y); s[6] = f2bf(f1.z); s[7] = f2bf(f1.w);
                *(bh8*)(A + row * MP + 128 + p * 32 + q * 8) = s;
            }
        } else {
            int4 z4 = make_int4(0, 0, 0, 0);
#pragma unroll
            for (int q = 0; q < 8; q++) *(int4*)(A + row * MP + (p * 8 + q) * 8) = z4;
        }
    }
    __syncthreads();

    {
        f32x4 acc[4][4];
#pragma unroll
        for (int a = 0; a < 4; a++)
#pragma unroll
            for (int b = 0; b < 4; b++) acc[a][b] = (f32x4)(0.f);

        const short* a_base = W1T + (size_t)(wv * 64 + lr) * 256 + lq * 8;
        for (int ks = 0; ks < 256; ks += 32) {
            bh8 af[4], bf[4];
#pragma unroll
            for (int mt = 0; mt < 4; mt++) af[mt] = *(const bh8*)(a_base + mt * 16 * 256 + ks);
#pragma unroll
            for (int nt = 0; nt < 4; nt++)
                bf[nt] = *(const bh8*)(A + (nt * 16 + lr) * MP + ks + lq * 8);
#pragma unroll
            for (int mt = 0; mt < 4; mt++)
#pragma unroll
                for (int nt = 0; nt < 4; nt++)
                    acc[mt][nt] = __builtin_amdgcn_mfma_f32_16x16x32_bf16(af[mt], bf[nt],
                                                                          acc[mt][nt], 0, 0, 0);
        }
#pragma unroll
        for (int mt = 0; mt < 4; mt++) {
            int h0 = wv * 64 + mt * 16 + lq * 4;
            float4 bb = *(const float4*)(b1 + h0);
#pragma unroll
            for (int nt = 0; nt < 4; nt++) {
                int e = nt * 16 + lr;
                bh4 pk;
                pk[0] = f2bf(swish_f(acc[mt][nt][0] + bb.x));
                pk[1] = f2bf(swish_f(acc[mt][nt][1] + bb.y));
                pk[2] = f2bf(swish_f(acc[mt][nt][2] + bb.z));
                pk[3] = f2bf(swish_f(acc[mt][nt][3] + bb.w));
                *(bh4*)(H + e * MP + h0) = pk;
            }
        }
    }
    __syncthreads();

    {
        f32x4 acc[2][4];
#pragma unroll
        for (int a = 0; a < 2; a++)
#pragma unroll
            for (int b = 0; b < 4; b++) acc[a][b] = (f32x4)(0.f);

        const short* a_base = W2T + (size_t)(wv * 32 + lr) * 256 + lq * 8;
        for (int ks = 0; ks < 256; ks += 32) {
            bh8 af[2], bf[4];
#pragma unroll
            for (int mt = 0; mt < 2; mt++) af[mt] = *(const bh8*)(a_base + mt * 16 * 256 + ks);
#pragma unroll
            for (int nt = 0; nt < 4; nt++)
                bf[nt] = *(const bh8*)(H + (nt * 16 + lr) * MP + ks + lq * 8);
#pragma unroll
            for (int mt = 0; mt < 2; mt++)
#pragma unroll
                for (int nt = 0; nt < 4; nt++)
                    acc[mt][nt] = __builtin_amdgcn_mfma_f32_16x16x32_bf16(af[mt], bf[nt],
                                                                          acc[mt][nt], 0, 0, 0);
        }
#pragma unroll
        for (int mt = 0; mt < 2; mt++) {
            int c0 = wv * 32 + mt * 16 + lq * 4;
            float4 bb = *(const float4*)(b2 + c0);
#pragma unroll
            for (int nt = 0; nt < 4; nt++) {
                int nl = nt * 16 + lr;
                int gn = n0 + nl;
                if (gn < N_NODES) {
                    float4 xv = *(const float4*)(x + (size_t)gn * 128 + c0);
                    float4 nv;
                    nv.x = xv.x + acc[mt][nt][0] + bb.x;
                    nv.y = xv.y + acc[mt][nt][1] + bb.y;
                    nv.z = xv.z + acc[mt][nt][2] + bb.z;
                    nv.w = xv.w + acc[mt][nt][3] + bb.w;
                    *(float4*)(x + (size_t)gn * 128 + c0) = nv;
                    bh4 pk;
                    pk[0] = f2bf(nv.x); pk[1] = f2bf(nv.y); pk[2] = f2bf(nv.z); pk[3] = f2bf(nv.w);
                    *(bh4*)(xb + (size_t)gn * 128 + c0) = pk;
                }
            }
        }
    }
}

// Output head (fp32)
__global__ __launch_bounds__(256, 4) void out_kernel(
    const float* __restrict__ x, const float* __restrict__ w1, const float* __restrict__ b1,
    const float* __restrict__ w2, const float* __restrict__ b2,
    const int* __restrict__ batch, float* __restrict__ out) {
    __shared__ float xr[4][128];
    __shared__ float red[4][4];
    const int tid = threadIdx.x;
    const int n0 = blockIdx.x * 4;

    {
        int i1 = tid;
        int nl1 = i1 >> 7, c1 = i1 & 127;
        int g1 = n0 + nl1;
        xr[nl1][c1] = (g1 < N_NODES) ? x[(size_t)g1 * 128 + c1] : 0.f;
        int i2 = tid + 256;
        int nl2 = i2 >> 7, c2 = i2 & 127;
        int g2 = n0 + nl2;
        xr[nl2][c2] = (g2 < N_NODES) ? x[(size_t)g2 * 128 + c2] : 0.f;
    }
    __syncthreads();

    float acc[4] = {0.f, 0.f, 0.f, 0.f};
    for (int k = 0; k < 128; k += 4) {
#pragma unroll
        for (int kk = 0; kk < 4; kk++) {
            float w = w1[(size_t)(k + kk) * 256 + tid];
            acc[0] += xr[0][k + kk] * w;
            acc[1] += xr[1][k + kk] * w;
            acc[2] += xr[2][k + kk] * w;
            acc[3] += xr[3][k + kk] * w;
        }
    }
    float bb = b1[tid];
    float wc = w2[tid];
    float val[4];
#pragma unroll
    for (int nn = 0; nn < 4; nn++) val[nn] = swish_f(acc[nn] + bb) * wc;

#pragma unroll
    for (int off = 32; off > 0; off >>= 1) {
#pragma unroll
        for (int nn = 0; nn < 4; nn++) val[nn] += __shfl_down(val[nn], off, 64);
    }
    int wid = tid >> 6;
    if ((tid & 63) == 0) {
#pragma unroll
        for (int nn = 0; nn < 4; nn++) red[wid][nn] = val[nn];
    }
    __syncthreads();
    if (tid < 4) {
        int gn = n0 + tid;
        if (gn < N_NODES) {
            float t = red[0][tid] + red[1][tid] + red[2][tid] + red[3][tid] + b2[0];
            atomicAdd(&out[batch[gn]], t);
        }
    }
}

extern "C" void kernel_launch(void* const* d_in, const int* in_sizes, int n_in,
                              void* d_out, int out_size, void* d_ws, size_t ws_size,
                              hipStream_t stream) {
    const float* positions = (const float*)d_in[0];
    const float* edge_shift = (const float*)d_in[1];
    const float* lattice = (const float*)d_in[2];
    const int* atomic_numbers = (const int*)d_in[3];
    const int* edge_index = (const int*)d_in[4];
    const int* batch = (const int*)d_in[5];
    const float* embed_w = (const float*)d_in[6];
    const float* edge_w1 = (const float*)d_in[7];
    const float* edge_b1 = (const float*)d_in[8];
    const float* edge_w2 = (const float*)d_in[9];
    const float* edge_b2 = (const float*)d_in[10];
    const float* node_w1 = (const float*)d_in[11];
    const float* node_b1 = (const float*)d_in[12];
    const float* node_w2 = (const float*)d_in[13];
    const float* node_b2 = (const float*)d_in[14];
    const float* out_w1 = (const float*)d_in[15];
    const float* out_b1 = (const float*)d_in[16];
    const float* out_w2 = (const float*)d_in[17];
    const float* out_b2 = (const float*)d_in[18];

    // workspace layout
    float* ws = (float*)d_ws;
    float* x = ws;                               // N*128 f32
    float* agg = x + (size_t)N_NODES * 128;      // N*128 f32
    float* d2 = agg + (size_t)N_NODES * 128;     // E f32
    short* xb = (short*)(d2 + N_EDGES);          // N*128 bf16
    short* eW1T = xb + (size_t)N_NODES * 128;    // 3*256*288
    short* eW2T = eW1T + 3 * 256 * 288;          // 3*128*256
    short* nW1T = eW2T + 3 * 128 * 256;          // 3*256*256
    short* nW2T = nW1T + 3 * 256 * 256;          // 3*128*256
    int* deg = (int*)(nW2T + 3 * 128 * 256);     // N
    int* fillc = deg + N_NODES;                  // N
    int* sc = fillc + N_NODES;                   // N
    int* bsum = sc + N_NODES;                    // 128
    int* esorted = bsum + 128;                   // E
    int* rowptr = esorted + N_EDGES;             // N+1

    (void)hipMemsetAsync(d_out, 0, (size_t)out_size * sizeof(float), stream);
    (void)hipMemsetAsync(deg, 0, N_NODES * sizeof(int), stream);
    (void)hipMemsetAsync(fillc, 0, N_NODES * sizeof(int), stream);

    // weight transpose+cvt (tiny)
    {
        int t1 = 3 * 256 * 288;
        cvt_wT_kernel<<<(t1 + 255) / 256, 256, 0, stream>>>(edge_w1, eW1T, 257, 256, 288, t1);
        int t2 = 3 * 128 * 256;
        cvt_wT_kernel<<<(t2 + 255) / 256, 256, 0, stream>>>(edge_w2, eW2T, 256, 128, 256, t2);
        int t3 = 3 * 256 * 256;
        cvt_wT_kernel<<<(t3 + 255) / 256, 256, 0, stream>>>(node_w1, nW1T, 256, 256, 256, t3);
        cvt_wT_kernel<<<(t2 + 255) / 256, 256, 0, stream>>>(node_w2, nW2T, 256, 128, 256, t2);
    }

    prep_kernel<<<(N_EDGES + 255) / 256, 256, 0, stream>>>(positions, edge_shift, lattice,
                                                           edge_index, batch, d2);
    embed_kernel<<<(N_NODES * 128) / 256, 256, 0, stream>>>(embed_w, atomic_numbers, x, xb);

    // CSR counting sort by dst
    {
        int nscan = (N_NODES + SCAN_BS - 1) / SCAN_BS;  // 98
        hist_kernel<<<(N_EDGES + 255) / 256, 256, 0, stream>>>(edge_index, deg);
        scan1_kernel<<<nscan, SCAN_BS, 0, stream>>>(deg, sc, bsum, N_NODES);
        scan2_kernel<<<1, 128, 0, stream>>>(bsum, nscan);
        scan3_kernel<<<(N_NODES + SCAN_BS) / SCAN_BS + 1, SCAN_BS, 0, stream>>>(
            sc, deg, bsum, rowptr, N_NODES, N_EDGES);
        fill_kernel<<<(N_EDGES + 255) / 256, 256, 0, stream>>>(edge_index, rowptr, fillc,
                                                               esorted);
    }

    for (int l = 0; l < N_LAYERS; l++) {
        (void)hipMemsetAsync(agg, 0, (size_t)N_NODES * 128 * sizeof(float), stream);
        edge_mlp_mfma<<<N_EDGES / 64, 256, 0, stream>>>(
            xb, d2, edge_index, esorted,
            eW1T + (size_t)l * 256 * 288, edge_b1 + (size_t)l * 256,
            eW2T + (size_t)l * 128 * 256, edge_b2 + (size_t)l * 128, agg);
        node_mlp_mfma<<<(N_NODES + 63) / 64, 256, 0, stream>>>(
            x, xb, agg,
            nW1T + (size_t)l * 256 * 256, node_b1 + (size_t)l * 256,
            nW2T + (size_t)l * 128 * 256, node_b2 + (size_t)l * 128);
    }
    out_kernel<<<N_NODES / 4, 256, 0, stream>>>(x, out_w1, out_b1, out_w2, out_b2, batch,
                                                (float*)d_out);
}

// Round 5
// 1533.889 us; speedup vs baseline: 5.4773x; 1.2926x over previous
//
#include <hip/hip_runtime.h>
#include <hip/hip_bf16.h>

#define N_NODES 50000
#define N_EDGES 800000
#define N_GRAPHS 32
#define NODE_DIM 128
#define HIDDEN 256
#define N_LAYERS 3

typedef __attribute__((ext_vector_type(8))) short bh8;   // 8 bf16 (4 VGPRs)
typedef __attribute__((ext_vector_type(4))) short bh4;   // 4 bf16 (8B)
typedef __attribute__((ext_vector_type(4))) float f32x4; // MFMA acc

#define AP 296  // edge A-tile pitch (bf16)
#define MP 264  // M/H tile pitch (bf16)
#define SP 132  // S tile pitch (fp32)
#define SCAN_BS 512
#define OB2 32  // out_stage2 blocks

__device__ __forceinline__ float swish_f(float v) { return v / (1.0f + __expf(-v)); }

__device__ __forceinline__ short f2bf(float f) {
    union { float f; unsigned u; } v;
    v.f = f;
    unsigned r = v.u + 0x7FFF + ((v.u >> 16) & 1);  // RNE
    return (short)(r >> 16);
}

// d2[e] = |pos[dst] - pos[src] + shift @ lattice[batch[src]]|^2
__global__ void prep_kernel(const float* __restrict__ pos, const float* __restrict__ shift,
                            const float* __restrict__ lattice, const int* __restrict__ eidx,
                            const int* __restrict__ batch, float* __restrict__ d2) {
    int e = blockIdx.x * blockDim.x + threadIdx.x;
    if (e >= N_EDGES) return;
    int s = eidx[e];
    int d = eidx[N_EDGES + e];
    int b = batch[s];
    const float* lat = lattice + b * 9;
    float s0 = shift[e * 3 + 0], s1 = shift[e * 3 + 1], s2 = shift[e * 3 + 2];
    float acc = 0.f;
#pragma unroll
    for (int j = 0; j < 3; j++) {
        float v = pos[d * 3 + j] - pos[s * 3 + j] + s0 * lat[j] + s1 * lat[3 + j] + s2 * lat[6 + j];
        acc += v * v;
    }
    d2[e] = acc;
}

// x[n][c] = embed[z[n]][c]; also bf16 mirror
__global__ void embed_kernel(const float* __restrict__ emb, const int* __restrict__ z,
                             float* __restrict__ x, short* __restrict__ xb) {
    int i = blockIdx.x * blockDim.x + threadIdx.x;
    int n = i >> 7, c = i & 127;
    float v = emb[z[n] * 128 + c];
    x[i] = v;
    xb[i] = f2bf(v);
}

// out[l][h][k] = bf16(in[l][k][h]) for k<K_in else 0
__global__ void cvt_wT_kernel(const float* __restrict__ in, short* __restrict__ out,
                              int K_in, int H, int K_pad, int total) {
    int i = blockIdx.x * blockDim.x + threadIdx.x;
    if (i >= total) return;
    int k = i % K_pad;
    int t = i / K_pad;
    int h = t % H;
    int l = t / H;
    out[i] = (k < K_in) ? f2bf(in[((size_t)l * K_in + k) * H + h]) : (short)0;
}

// ---- CSR counting-sort build ----
__global__ void hist_kernel(const int* __restrict__ eidx, int* __restrict__ deg) {
    int e = blockIdx.x * blockDim.x + threadIdx.x;
    if (e >= N_EDGES) return;
    atomicAdd(&deg[eidx[N_EDGES + e]], 1);
}

__global__ void scan1_kernel(const int* __restrict__ deg, int* __restrict__ sc,
                             int* __restrict__ bsum, int n) {
    __shared__ int s[SCAN_BS];
    int i = blockIdx.x * SCAN_BS + threadIdx.x;
    int v = (i < n) ? deg[i] : 0;
    s[threadIdx.x] = v;
    __syncthreads();
    for (int off = 1; off < SCAN_BS; off <<= 1) {
        int t = (threadIdx.x >= off) ? s[threadIdx.x - off] : 0;
        __syncthreads();
        s[threadIdx.x] += t;
        __syncthreads();
    }
    if (i < n) sc[i] = s[threadIdx.x];
    if (threadIdx.x == SCAN_BS - 1) bsum[blockIdx.x] = s[SCAN_BS - 1];
}

__global__ void scan2_kernel(int* __restrict__ bsum, int nb) {  // 1 block, 128 threads
    __shared__ int s[128];
    int v = (threadIdx.x < nb) ? bsum[threadIdx.x] : 0;
    s[threadIdx.x] = v;
    __syncthreads();
    for (int off = 1; off < 128; off <<= 1) {
        int t = (threadIdx.x >= off) ? s[threadIdx.x - off] : 0;
        __syncthreads();
        s[threadIdx.x] += t;
        __syncthreads();
    }
    if (threadIdx.x < nb) bsum[threadIdx.x] = s[threadIdx.x];
}

__global__ void scan3_kernel(const int* __restrict__ sc, const int* __restrict__ deg,
                             const int* __restrict__ bsum, int* __restrict__ rowptr,
                             int n, int total) {
    int i = blockIdx.x * SCAN_BS + threadIdx.x;
    if (i > n) return;
    if (i == n) { rowptr[n] = total; return; }
    int off = (blockIdx.x > 0) ? bsum[blockIdx.x - 1] : 0;
    rowptr[i] = sc[i] - deg[i] + off;
}

__global__ void fill_kernel(const int* __restrict__ eidx, const int* __restrict__ rowptr,
                            int* __restrict__ fillc, int* __restrict__ esorted) {
    int e = blockIdx.x * blockDim.x + threadIdx.x;
    if (e >= N_EDGES) return;
    int d = eidx[N_EDGES + e];
    int p = rowptr[d] + atomicAdd(&fillc[d], 1);
    esorted[p] = e;
}

// ---------------- Edge MLP (MFMA, dst-sorted, segmented-reduction scatter) ----------------
__global__ __launch_bounds__(256, 2) void edge_mlp_mfma(
    const short* __restrict__ xb, const float* __restrict__ d2,
    const int* __restrict__ eidx, const int* __restrict__ esorted,
    const short* __restrict__ W1T,  // [256][288] bf16
    const float* __restrict__ b1,
    const short* __restrict__ W2T,  // [128][256] bf16
    const float* __restrict__ b2,
    float* __restrict__ agg) {
    __shared__ short A[64 * AP];   // reused as S (fp32 [64][SP]) after GEMM1
    __shared__ short M[64 * MP];
    __shared__ int s_dst[64];
    float* S = (float*)A;
    const int tid = threadIdx.x;
    const int e0 = blockIdx.x * 64;
    const int wv = tid >> 6;
    const int ln = tid & 63;
    const int lr = ln & 15;
    const int lq = ln >> 4;

    // ---- stage A: sorted-edge gather ----
    {
        int el = tid >> 2, p = tid & 3;
        int ge = esorted[e0 + el];
        int s = eidx[ge];
        int d = eidx[N_EDGES + ge];
        const int4* xd = (const int4*)(xb + (size_t)d * 128);
        const int4* xs = (const int4*)(xb + (size_t)s * 128);
#pragma unroll
        for (int q = 0; q < 4; q++) {
            int c = p * 4 + q;
            *(int4*)(A + el * AP + c * 8) = xd[c];
            *(int4*)(A + el * AP + 128 + c * 8) = xs[c];
        }
        if (p == 0) {
            s_dst[el] = d;
            union { int4 v; short s[8]; } z;
            int4 z4 = make_int4(0, 0, 0, 0);
            z.v = z4;
            short* t = A + el * AP + 256;
            *(int4*)(t + 8) = z4;
            *(int4*)(t + 16) = z4;
            *(int4*)(t + 24) = z4;
            z.s[0] = f2bf(d2[ge]);
            *(int4*)t = z.v;
        }
    }
    __syncthreads();

    // ---- GEMM1 + swish -> M ----
    {
        f32x4 acc[4][4];
#pragma unroll
        for (int a = 0; a < 4; a++)
#pragma unroll
            for (int b = 0; b < 4; b++) acc[a][b] = (f32x4)(0.f);

        const short* a_base = W1T + (size_t)(wv * 64 + lr) * 288 + lq * 8;
        for (int ks = 0; ks < 288; ks += 32) {
            bh8 af[4], bf[4];
#pragma unroll
            for (int mt = 0; mt < 4; mt++) af[mt] = *(const bh8*)(a_base + mt * 16 * 288 + ks);
#pragma unroll
            for (int nt = 0; nt < 4; nt++)
                bf[nt] = *(const bh8*)(A + (nt * 16 + lr) * AP + ks + lq * 8);
#pragma unroll
            for (int mt = 0; mt < 4; mt++)
#pragma unroll
                for (int nt = 0; nt < 4; nt++)
                    acc[mt][nt] = __builtin_amdgcn_mfma_f32_16x16x32_bf16(af[mt], bf[nt],
                                                                          acc[mt][nt], 0, 0, 0);
        }
#pragma unroll
        for (int mt = 0; mt < 4; mt++) {
            int h0 = wv * 64 + mt * 16 + lq * 4;
            float4 bb = *(const float4*)(b1 + h0);
#pragma unroll
            for (int nt = 0; nt < 4; nt++) {
                int e = nt * 16 + lr;
                bh4 pk;
                pk[0] = f2bf(swish_f(acc[mt][nt][0] + bb.x));
                pk[1] = f2bf(swish_f(acc[mt][nt][1] + bb.y));
                pk[2] = f2bf(swish_f(acc[mt][nt][2] + bb.z));
                pk[3] = f2bf(swish_f(acc[mt][nt][3] + bb.w));
                *(bh4*)(M + e * MP + h0) = pk;
            }
        }
    }
    __syncthreads();   // GEMM1 A-reads done; A space free for S

    // ---- GEMM2 + swish -> S (fp32, LDS) ----
    {
        f32x4 acc[2][4];
#pragma unroll
        for (int a = 0; a < 2; a++)
#pragma unroll
            for (int b = 0; b < 4; b++) acc[a][b] = (f32x4)(0.f);

        const short* a_base = W2T + (size_t)(wv * 32 + lr) * 256 + lq * 8;
        for (int ks = 0; ks < 256; ks += 32) {
            bh8 af[2], bf[4];
#pragma unroll
            for (int mt = 0; mt < 2; mt++) af[mt] = *(const bh8*)(a_base + mt * 16 * 256 + ks);
#pragma unroll
            for (int nt = 0; nt < 4; nt++)
                bf[nt] = *(const bh8*)(M + (nt * 16 + lr) * MP + ks + lq * 8);
#pragma unroll
            for (int mt = 0; mt < 2; mt++)
#pragma unroll
                for (int nt = 0; nt < 4; nt++)
                    acc[mt][nt] = __builtin_amdgcn_mfma_f32_16x16x32_bf16(af[mt], bf[nt],
                                                                          acc[mt][nt], 0, 0, 0);
        }
#pragma unroll
        for (int mt = 0; mt < 2; mt++) {
            int c0 = wv * 32 + mt * 16 + lq * 4;
            float4 bb = *(const float4*)(b2 + c0);
#pragma unroll
            for (int nt = 0; nt < 4; nt++) {
                int e = nt * 16 + lr;
                float4 sv;
                sv.x = swish_f(acc[mt][nt][0] + bb.x);
                sv.y = swish_f(acc[mt][nt][1] + bb.y);
                sv.z = swish_f(acc[mt][nt][2] + bb.z);
                sv.w = swish_f(acc[mt][nt][3] + bb.w);
                *(float4*)&S[e * SP + c0] = sv;
            }
        }
    }
    __syncthreads();

    // ---- segmented reduction over sorted dst; one atomic per run ----
    {
        const int c = tid & 127;
        const int half = tid >> 7;
        const int eb = half * 32;
        int cur = s_dst[eb];
        float acc = S[eb * SP + c];
        for (int e2 = eb + 1; e2 < eb + 32; ++e2) {
            int dn = s_dst[e2];
            float v = S[e2 * SP + c];
            if (dn != cur) {
                atomicAdd(agg + (size_t)cur * 128 + c, acc);
                acc = v;
                cur = dn;
            } else {
                acc += v;
            }
        }
        atomicAdd(agg + (size_t)cur * 128 + c, acc);
    }
}

// ---------------- Node MLP (MFMA) ----------------
__global__ __launch_bounds__(256, 2) void node_mlp_mfma(
    float* __restrict__ x, short* __restrict__ xb, const float* __restrict__ agg,
    const short* __restrict__ W1T, const float* __restrict__ b1,
    const short* __restrict__ W2T, const float* __restrict__ b2) {
    __shared__ short A[64 * MP];
    __shared__ short H[64 * MP];
    const int tid = threadIdx.x;
    const int n0 = blockIdx.x * 64;
    const int wv = tid >> 6;
    const int ln = tid & 63;
    const int lr = ln & 15;
    const int lq = ln >> 4;

    {
        int row = tid >> 2, p = tid & 3;
        int gn = n0 + row;
        if (gn < N_NODES) {
            const int4* xp = (const int4*)(xb + (size_t)gn * 128);
#pragma unroll
            for (int q = 0; q < 4; q++) {
                int c = p * 4 + q;
                *(int4*)(A + row * MP + c * 8) = xp[c];
            }
            const float4* ap = (const float4*)(agg + (size_t)gn * 128);
#pragma unroll
            for (int q = 0; q < 4; q++) {
                float4 f0 = ap[p * 8 + q * 2];
                float4 f1 = ap[p * 8 + q * 2 + 1];
                bh8 s;
                s[0] = f2bf(f0.x); s[1] = f2bf(f0.y); s[2] = f2bf(f0.z); s[3] = f2bf(f0.w);
                s[4] = f2bf(f1.x); s[5] = f2bf(f1.y); s[6] = f2bf(f1.z); s[7] = f2bf(f1.w);
                *(bh8*)(A + row * MP + 128 + p * 32 + q * 8) = s;
            }
        } else {
            int4 z4 = make_int4(0, 0, 0, 0);
#pragma unroll
            for (int q = 0; q < 8; q++) *(int4*)(A + row * MP + (p * 8 + q) * 8) = z4;
        }
    }
    __syncthreads();

    {
        f32x4 acc[4][4];
#pragma unroll
        for (int a = 0; a < 4; a++)
#pragma unroll
            for (int b = 0; b < 4; b++) acc[a][b] = (f32x4)(0.f);

        const short* a_base = W1T + (size_t)(wv * 64 + lr) * 256 + lq * 8;
        for (int ks = 0; ks < 256; ks += 32) {
            bh8 af[4], bf[4];
#pragma unroll
            for (int mt = 0; mt < 4; mt++) af[mt] = *(const bh8*)(a_base + mt * 16 * 256 + ks);
#pragma unroll
            for (int nt = 0; nt < 4; nt++)
                bf[nt] = *(const bh8*)(A + (nt * 16 + lr) * MP + ks + lq * 8);
#pragma unroll
            for (int mt = 0; mt < 4; mt++)
#pragma unroll
                for (int nt = 0; nt < 4; nt++)
                    acc[mt][nt] = __builtin_amdgcn_mfma_f32_16x16x32_bf16(af[mt], bf[nt],
                                                                          acc[mt][nt], 0, 0, 0);
        }
#pragma unroll
        for (int mt = 0; mt < 4; mt++) {
            int h0 = wv * 64 + mt * 16 + lq * 4;
            float4 bb = *(const float4*)(b1 + h0);
#pragma unroll
            for (int nt = 0; nt < 4; nt++) {
                int e = nt * 16 + lr;
                bh4 pk;
                pk[0] = f2bf(swish_f(acc[mt][nt][0] + bb.x));
                pk[1] = f2bf(swish_f(acc[mt][nt][1] + bb.y));
                pk[2] = f2bf(swish_f(acc[mt][nt][2] + bb.z));
                pk[3] = f2bf(swish_f(acc[mt][nt][3] + bb.w));
                *(bh4*)(H + e * MP + h0) = pk;
            }
        }
    }
    __syncthreads();

    {
        f32x4 acc[2][4];
#pragma unroll
        for (int a = 0; a < 2; a++)
#pragma unroll
            for (int b = 0; b < 4; b++) acc[a][b] = (f32x4)(0.f);

        const short* a_base = W2T + (size_t)(wv * 32 + lr) * 256 + lq * 8;
        for (int ks = 0; ks < 256; ks += 32) {
            bh8 af[2], bf[4];
#pragma unroll
            for (int mt = 0; mt < 2; mt++) af[mt] = *(const bh8*)(a_base + mt * 16 * 256 + ks);
#pragma unroll
            for (int nt = 0; nt < 4; nt++)
                bf[nt] = *(const bh8*)(H + (nt * 16 + lr) * MP + ks + lq * 8);
#pragma unroll
            for (int mt = 0; mt < 2; mt++)
#pragma unroll
                for (int nt = 0; nt < 4; nt++)
                    acc[mt][nt] = __builtin_amdgcn_mfma_f32_16x16x32_bf16(af[mt], bf[nt],
                                                                          acc[mt][nt], 0, 0, 0);
        }
#pragma unroll
        for (int mt = 0; mt < 2; mt++) {
            int c0 = wv * 32 + mt * 16 + lq * 4;
            float4 bb = *(const float4*)(b2 + c0);
#pragma unroll
            for (int nt = 0; nt < 4; nt++) {
                int nl = nt * 16 + lr;
                int gn = n0 + nl;
                if (gn < N_NODES) {
                    float4 xv = *(const float4*)(x + (size_t)gn * 128 + c0);
                    float4 nv;
                    nv.x = xv.x + acc[mt][nt][0] + bb.x;
                    nv.y = xv.y + acc[mt][nt][1] + bb.y;
                    nv.z = xv.z + acc[mt][nt][2] + bb.z;
                    nv.w = xv.w + acc[mt][nt][3] + bb.w;
                    *(float4*)(x + (size_t)gn * 128 + c0) = nv;
                    bh4 pk;
                    pk[0] = f2bf(nv.x); pk[1] = f2bf(nv.y); pk[2] = f2bf(nv.z); pk[3] = f2bf(nv.w);
                    *(bh4*)(xb + (size_t)gn * 128 + c0) = pk;
                }
            }
        }
    }
}

// ---------------- Output head, atomic-free 3-stage ----------------
// Stage 1: per-node scalar sval[n] = swish(x@w1+b1) @ w2 + b2   (32 nodes/block)
__global__ __launch_bounds__(256, 4) void out_stage1(
    const float* __restrict__ x, const float* __restrict__ w1, const float* __restrict__ b1,
    const float* __restrict__ w2, const float* __restrict__ b2, float* __restrict__ sval) {
    __shared__ float xr[32][128];
    __shared__ float red[4][32];
    const int tid = threadIdx.x;
    const int n0 = blockIdx.x * 32;

    {
        const float4* xs = (const float4*)(x + (size_t)n0 * 128);
        if (n0 + 32 <= N_NODES) {
#pragma unroll
            for (int q = 0; q < 4; q++) {
                int i = tid + q * 256;
                ((float4*)xr)[i] = xs[i];
            }
        } else {
#pragma unroll
            for (int q = 0; q < 4; q++) {
                int i = tid + q * 256;
                int nn = i >> 5;  // 32 float4 per row
                ((float4*)xr)[i] = (n0 + nn < N_NODES) ? xs[i] : make_float4(0.f, 0.f, 0.f, 0.f);
            }
        }
    }
    __syncthreads();

    float acc[32];
#pragma unroll
    for (int nn = 0; nn < 32; nn++) acc[nn] = 0.f;

    for (int k = 0; k < 128; k += 4) {
        float w_[4];
#pragma unroll
        for (int kk = 0; kk < 4; kk++) w_[kk] = w1[(size_t)(k + kk) * 256 + tid];
#pragma unroll
        for (int nn = 0; nn < 32; nn++) {
            float4 xv = *(const float4*)&xr[nn][k];
            acc[nn] += xv.x * w_[0] + xv.y * w_[1] + xv.z * w_[2] + xv.w * w_[3];
        }
    }

    const float bb = b1[tid];
    const float wc = w2[tid];
    const int lane = tid & 63, wvi = tid >> 6;
#pragma unroll
    for (int nn = 0; nn < 32; nn++) {
        float v = swish_f(acc[nn] + bb) * wc;
#pragma unroll
        for (int off = 32; off > 0; off >>= 1) v += __shfl_down(v, off, 64);
        if (lane == 0) red[wvi][nn] = v;
    }
    __syncthreads();
    if (tid < 32) {
        int gn = n0 + tid;
        if (gn < N_NODES)
            sval[gn] = red[0][tid] + red[1][tid] + red[2][tid] + red[3][tid] + b2[0];
    }
}

// Stage 2: 32 blocks; per-block per-graph partials via run-length flush (batch sorted)
__global__ void out_stage2(const float* __restrict__ sval, const int* __restrict__ batch,
                           float* __restrict__ partial) {
    __shared__ float part[N_GRAPHS];
    const int tid = threadIdx.x;
    if (tid < N_GRAPHS) part[tid] = 0.f;
    __syncthreads();
    const int per_block = (N_NODES + OB2 - 1) / OB2;           // 1563
    const int start = blockIdx.x * per_block;
    const int end = min(start + per_block, N_NODES);
    const int per_thread = (per_block + 255) / 256;            // 7
    int s = start + tid * per_thread;
    int e = min(s + per_thread, end);
    if (s < e) {
        int g = batch[s];
        float a = sval[s];
        for (int n = s + 1; n < e; n++) {
            int gg = batch[n];
            float v = sval[n];
            if (gg != g) {
                atomicAdd(&part[g], a);
                a = v;
                g = gg;
            } else {
                a += v;
            }
        }
        atomicAdd(&part[g], a);
    }
    __syncthreads();
    if (tid < N_GRAPHS) partial[blockIdx.x * N_GRAPHS + tid] = part[tid];
}

// Stage 3: final sum over 32 partial rows
__global__ void out_stage3(const float* __restrict__ partial, float* __restrict__ out) {
    int g = threadIdx.x;
    if (g >= N_GRAPHS) return;
    float s = 0.f;
    for (int b = 0; b < OB2; b++) s += partial[b * N_GRAPHS + g];
    out[g] = s;
}

extern "C" void kernel_launch(void* const* d_in, const int* in_sizes, int n_in,
                              void* d_out, int out_size, void* d_ws, size_t ws_size,
                              hipStream_t stream) {
    const float* positions = (const float*)d_in[0];
    const float* edge_shift = (const float*)d_in[1];
    const float* lattice = (const float*)d_in[2];
    const int* atomic_numbers = (const int*)d_in[3];
    const int* edge_index = (const int*)d_in[4];
    const int* batch = (const int*)d_in[5];
    const float* embed_w = (const float*)d_in[6];
    const float* edge_w1 = (const float*)d_in[7];
    const float* edge_b1 = (const float*)d_in[8];
    const float* edge_w2 = (const float*)d_in[9];
    const float* edge_b2 = (const float*)d_in[10];
    const float* node_w1 = (const float*)d_in[11];
    const float* node_b1 = (const float*)d_in[12];
    const float* node_w2 = (const float*)d_in[13];
    const float* node_b2 = (const float*)d_in[14];
    const float* out_w1 = (const float*)d_in[15];
    const float* out_b1 = (const float*)d_in[16];
    const float* out_w2 = (const float*)d_in[17];
    const float* out_b2 = (const float*)d_in[18];

    // workspace layout
    float* ws = (float*)d_ws;
    float* x = ws;                               // N*128 f32
    float* agg = x + (size_t)N_NODES * 128;      // N*128 f32
    float* d2 = agg + (size_t)N_NODES * 128;     // E f32
    short* xb = (short*)(d2 + N_EDGES);          // N*128 bf16
    short* eW1T = xb + (size_t)N_NODES * 128;    // 3*256*288
    short* eW2T = eW1T + 3 * 256 * 288;          // 3*128*256
    short* nW1T = eW2T + 3 * 128 * 256;          // 3*256*256
    short* nW2T = nW1T + 3 * 256 * 256;          // 3*128*256
    int* deg = (int*)(nW2T + 3 * 128 * 256);     // N
    int* fillc = deg + N_NODES;                  // N
    int* sc = fillc + N_NODES;                   // N
    int* bsum = sc + N_NODES;                    // 128
    int* esorted = bsum + 128;                   // E
    int* rowptr = esorted + N_EDGES;             // N+1
    float* sval = (float*)(rowptr + N_NODES + 1);  // N
    float* partial = sval + N_NODES;               // OB2*N_GRAPHS

    (void)hipMemsetAsync(deg, 0, N_NODES * sizeof(int), stream);
    (void)hipMemsetAsync(fillc, 0, N_NODES * sizeof(int), stream);

    // weight transpose+cvt (tiny)
    {
        int t1 = 3 * 256 * 288;
        cvt_wT_kernel<<<(t1 + 255) / 256, 256, 0, stream>>>(edge_w1, eW1T, 257, 256, 288, t1);
        int t2 = 3 * 128 * 256;
        cvt_wT_kernel<<<(t2 + 255) / 256, 256, 0, stream>>>(edge_w2, eW2T, 256, 128, 256, t2);
        int t3 = 3 * 256 * 256;
        cvt_wT_kernel<<<(t3 + 255) / 256, 256, 0, stream>>>(node_w1, nW1T, 256, 256, 256, t3);
        cvt_wT_kernel<<<(t2 + 255) / 256, 256, 0, stream>>>(node_w2, nW2T, 256, 128, 256, t2);
    }

    prep_kernel<<<(N_EDGES + 255) / 256, 256, 0, stream>>>(positions, edge_shift, lattice,
                                                           edge_index, batch, d2);
    embed_kernel<<<(N_NODES * 128) / 256, 256, 0, stream>>>(embed_w, atomic_numbers, x, xb);

    // CSR counting sort by dst
    {
        int nscan = (N_NODES + SCAN_BS - 1) / SCAN_BS;  // 98
        hist_kernel<<<(N_EDGES + 255) / 256, 256, 0, stream>>>(edge_index, deg);
        scan1_kernel<<<nscan, SCAN_BS, 0, stream>>>(deg, sc, bsum, N_NODES);
        scan2_kernel<<<1, 128, 0, stream>>>(bsum, nscan);
        scan3_kernel<<<(N_NODES + SCAN_BS) / SCAN_BS + 1, SCAN_BS, 0, stream>>>(
            sc, deg, bsum, rowptr, N_NODES, N_EDGES);
        fill_kernel<<<(N_EDGES + 255) / 256, 256, 0, stream>>>(edge_index, rowptr, fillc,
                                                               esorted);
    }

    for (int l = 0; l < N_LAYERS; l++) {
        (void)hipMemsetAsync(agg, 0, (size_t)N_NODES * 128 * sizeof(float), stream);
        edge_mlp_mfma<<<N_EDGES / 64, 256, 0, stream>>>(
            xb, d2, edge_index, esorted,
            eW1T + (size_t)l * 256 * 288, edge_b1 + (size_t)l * 256,
            eW2T + (size_t)l * 128 * 256, edge_b2 + (size_t)l * 128, agg);
        node_mlp_mfma<<<(N_NODES + 63) / 64, 256, 0, stream>>>(
            x, xb, agg,
            nW1T + (size_t)l * 256 * 256, node_b1 + (size_t)l * 256,
            nW2T + (size_t)l * 128 * 256, node_b2 + (size_t)l * 128);
    }
    out_stage1<<<(N_NODES + 31) / 32, 256, 0, stream>>>(x, out_w1, out_b1, out_w2, out_b2, sval);
    out_stage2<<<OB2, 256, 0, stream>>>(sval, batch, partial);
    out_stage3<<<1, 64, 0, stream>>>(partial, (float*)d_out);
}

// Round 6
// 1367.340 us; speedup vs baseline: 6.1445x; 1.1218x over previous
//
#include <hip/hip_runtime.h>
#include <hip/hip_bf16.h>

#define N_NODES 50000
#define N_EDGES 800000
#define N_GRAPHS 32
#define NODE_DIM 128
#define HIDDEN 256
#define N_LAYERS 3

typedef __attribute__((ext_vector_type(8))) short bh8;   // 8 bf16 (4 VGPRs)
typedef __attribute__((ext_vector_type(4))) short bh4;   // 4 bf16 (8B)
typedef __attribute__((ext_vector_type(4))) float f32x4; // MFMA acc

#define AP 296  // edge A-tile pitch (bf16); also the single shared buffer extent
#define MP 264  // M/H tile pitch (bf16)
#define EP 68   // S_t pitch (fp32, [c][e] layout): 68%32=4 -> bandwidth-floor optimal b128
#define SCAN_BS 512
#define OB2 32  // out_stage2 blocks

// swish via hw rcp (avoids full-precision fp32 divide sequence)
__device__ __forceinline__ float swish_f(float v) {
    return v * __builtin_amdgcn_rcpf(1.0f + __expf(-v));
}

// round-half-up bf16 (2 int ops; differs from RNE only on exact ties)
__device__ __forceinline__ short f2bf(float f) {
    union { float f; unsigned u; } v;
    v.f = f;
    return (short)((v.u + 0x8000u) >> 16);
}

// d2[e] = |pos[dst] - pos[src] + shift @ lattice[batch[src]]|^2
__global__ void prep_kernel(const float* __restrict__ pos, const float* __restrict__ shift,
                            const float* __restrict__ lattice, const int* __restrict__ eidx,
                            const int* __restrict__ batch, float* __restrict__ d2) {
    int e = blockIdx.x * blockDim.x + threadIdx.x;
    if (e >= N_EDGES) return;
    int s = eidx[e];
    int d = eidx[N_EDGES + e];
    int b = batch[s];
    const float* lat = lattice + b * 9;
    float s0 = shift[e * 3 + 0], s1 = shift[e * 3 + 1], s2 = shift[e * 3 + 2];
    float acc = 0.f;
#pragma unroll
    for (int j = 0; j < 3; j++) {
        float v = pos[d * 3 + j] - pos[s * 3 + j] + s0 * lat[j] + s1 * lat[3 + j] + s2 * lat[6 + j];
        acc += v * v;
    }
    d2[e] = acc;
}

// x[n][c] = embed[z[n]][c]; also bf16 mirror
__global__ void embed_kernel(const float* __restrict__ emb, const int* __restrict__ z,
                             float* __restrict__ x, short* __restrict__ xb) {
    int i = blockIdx.x * blockDim.x + threadIdx.x;
    int n = i >> 7, c = i & 127;
    float v = emb[z[n] * 128 + c];
    x[i] = v;
    xb[i] = f2bf(v);
}

// out[l][h][k] = bf16(in[l][k][h]) for k<K_in else 0
__global__ void cvt_wT_kernel(const float* __restrict__ in, short* __restrict__ out,
                              int K_in, int H, int K_pad, int total) {
    int i = blockIdx.x * blockDim.x + threadIdx.x;
    if (i >= total) return;
    int k = i % K_pad;
    int t = i / K_pad;
    int h = t % H;
    int l = t / H;
    out[i] = (k < K_in) ? f2bf(in[((size_t)l * K_in + k) * H + h]) : (short)0;
}

// ---- CSR counting-sort build ----
__global__ void hist_kernel(const int* __restrict__ eidx, int* __restrict__ deg) {
    int e = blockIdx.x * blockDim.x + threadIdx.x;
    if (e >= N_EDGES) return;
    atomicAdd(&deg[eidx[N_EDGES + e]], 1);
}

__global__ void scan1_kernel(const int* __restrict__ deg, int* __restrict__ sc,
                             int* __restrict__ bsum, int n) {
    __shared__ int s[SCAN_BS];
    int i = blockIdx.x * SCAN_BS + threadIdx.x;
    int v = (i < n) ? deg[i] : 0;
    s[threadIdx.x] = v;
    __syncthreads();
    for (int off = 1; off < SCAN_BS; off <<= 1) {
        int t = (threadIdx.x >= off) ? s[threadIdx.x - off] : 0;
        __syncthreads();
        s[threadIdx.x] += t;
        __syncthreads();
    }
    if (i < n) sc[i] = s[threadIdx.x];
    if (threadIdx.x == SCAN_BS - 1) bsum[blockIdx.x] = s[SCAN_BS - 1];
}

__global__ void scan2_kernel(int* __restrict__ bsum, int nb) {  // 1 block, 128 threads
    __shared__ int s[128];
    int v = (threadIdx.x < nb) ? bsum[threadIdx.x] : 0;
    s[threadIdx.x] = v;
    __syncthreads();
    for (int off = 1; off < 128; off <<= 1) {
        int t = (threadIdx.x >= off) ? s[threadIdx.x - off] : 0;
        __syncthreads();
        s[threadIdx.x] += t;
        __syncthreads();
    }
    if (threadIdx.x < nb) bsum[threadIdx.x] = s[threadIdx.x];
}

__global__ void scan3_kernel(const int* __restrict__ sc, const int* __restrict__ deg,
                             const int* __restrict__ bsum, int* __restrict__ rowptr,
                             int n, int total) {
    int i = blockIdx.x * SCAN_BS + threadIdx.x;
    if (i > n) return;
    if (i == n) { rowptr[n] = total; return; }
    int off = (blockIdx.x > 0) ? bsum[blockIdx.x - 1] : 0;
    rowptr[i] = sc[i] - deg[i] + off;
}

__global__ void fill_kernel(const int* __restrict__ eidx, const int* __restrict__ rowptr,
                            int* __restrict__ fillc, int* __restrict__ esorted) {
    int e = blockIdx.x * blockDim.x + threadIdx.x;
    if (e >= N_EDGES) return;
    int d = eidx[N_EDGES + e];
    int p = rowptr[d] + atomicAdd(&fillc[d], 1);
    esorted[p] = e;
}

// ---------------- Edge MLP (MFMA, dst-sorted, single LDS buffer, 4 blocks/CU) ----------------
// One 38KB buffer X time-shares: A [64][AP] -> M [64][MP] -> S_t [128][EP] (fp32, [c][e]).
__global__ __launch_bounds__(256, 4) void edge_mlp_mfma(
    const short* __restrict__ xb, const float* __restrict__ d2,
    const int* __restrict__ eidx, const int* __restrict__ esorted,
    const short* __restrict__ W1T,  // [256][288] bf16
    const float* __restrict__ b1,
    const short* __restrict__ W2T,  // [128][256] bf16
    const float* __restrict__ b2,
    float* __restrict__ agg) {
    __shared__ __align__(16) short X[64 * AP];
    __shared__ int s_dst[64];
    float* St = (float*)X;
    const int tid = threadIdx.x;
    const int e0 = blockIdx.x * 64;
    const int wv = tid >> 6;
    const int ln = tid & 63;
    const int lr = ln & 15;
    const int lq = ln >> 4;

    // ---- stage A: sorted-edge gather ----
    {
        int el = tid >> 2, p = tid & 3;
        int ge = esorted[e0 + el];
        int s = eidx[ge];
        int d = eidx[N_EDGES + ge];
        const int4* xd = (const int4*)(xb + (size_t)d * 128);
        const int4* xs = (const int4*)(xb + (size_t)s * 128);
#pragma unroll
        for (int q = 0; q < 4; q++) {
            int c = p * 4 + q;
            *(int4*)(X + el * AP + c * 8) = xd[c];
            *(int4*)(X + el * AP + 128 + c * 8) = xs[c];
        }
        if (p == 0) {
            s_dst[el] = d;
            union { int4 v; short s[8]; } z;
            int4 z4 = make_int4(0, 0, 0, 0);
            z.v = z4;
            short* t = X + el * AP + 256;
            *(int4*)(t + 8) = z4;
            *(int4*)(t + 16) = z4;
            *(int4*)(t + 24) = z4;
            z.s[0] = f2bf(d2[ge]);
            *(int4*)t = z.v;
        }
    }
    __syncthreads();

    // ---- GEMM1 (reads A) ----
    bh4 mv[4][4];
    {
        f32x4 acc[4][4];
#pragma unroll
        for (int a = 0; a < 4; a++)
#pragma unroll
            for (int b = 0; b < 4; b++) acc[a][b] = (f32x4)(0.f);

        const short* a_base = W1T + (size_t)(wv * 64 + lr) * 288 + lq * 8;
        for (int ks = 0; ks < 288; ks += 32) {
            bh8 af[4], bf[4];
#pragma unroll
            for (int mt = 0; mt < 4; mt++) af[mt] = *(const bh8*)(a_base + mt * 16 * 288 + ks);
#pragma unroll
            for (int nt = 0; nt < 4; nt++)
                bf[nt] = *(const bh8*)(X + (nt * 16 + lr) * AP + ks + lq * 8);
#pragma unroll
            for (int mt = 0; mt < 4; mt++)
#pragma unroll
                for (int nt = 0; nt < 4; nt++)
                    acc[mt][nt] = __builtin_amdgcn_mfma_f32_16x16x32_bf16(af[mt], bf[nt],
                                                                          acc[mt][nt], 0, 0, 0);
        }
        // swish + pack into registers (A still live in LDS)
#pragma unroll
        for (int mt = 0; mt < 4; mt++) {
            int h0 = wv * 64 + mt * 16 + lq * 4;
            float4 bb = *(const float4*)(b1 + h0);
#pragma unroll
            for (int nt = 0; nt < 4; nt++) {
                mv[mt][nt][0] = f2bf(swish_f(acc[mt][nt][0] + bb.x));
                mv[mt][nt][1] = f2bf(swish_f(acc[mt][nt][1] + bb.y));
                mv[mt][nt][2] = f2bf(swish_f(acc[mt][nt][2] + bb.z));
                mv[mt][nt][3] = f2bf(swish_f(acc[mt][nt][3] + bb.w));
            }
        }
    }
    __syncthreads();   // everyone done reading A -> buffer becomes M

    // ---- write M (aliases A space) ----
#pragma unroll
    for (int mt = 0; mt < 4; mt++) {
        int h0 = wv * 64 + mt * 16 + lq * 4;
#pragma unroll
        for (int nt = 0; nt < 4; nt++) {
            int e = nt * 16 + lr;
            *(bh4*)(X + e * MP + h0) = mv[mt][nt];
        }
    }
    __syncthreads();

    // ---- GEMM2 (reads M) ----
    float4 sv[2][4];
    {
        f32x4 acc[2][4];
#pragma unroll
        for (int a = 0; a < 2; a++)
#pragma unroll
            for (int b = 0; b < 4; b++) acc[a][b] = (f32x4)(0.f);

        const short* a_base = W2T + (size_t)(wv * 32 + lr) * 256 + lq * 8;
        for (int ks = 0; ks < 256; ks += 32) {
            bh8 af[2], bf[4];
#pragma unroll
            for (int mt = 0; mt < 2; mt++) af[mt] = *(const bh8*)(a_base + mt * 16 * 256 + ks);
#pragma unroll
            for (int nt = 0; nt < 4; nt++)
                bf[nt] = *(const bh8*)(X + (nt * 16 + lr) * MP + ks + lq * 8);
#pragma unroll
            for (int mt = 0; mt < 2; mt++)
#pragma unroll
                for (int nt = 0; nt < 4; nt++)
                    acc[mt][nt] = __builtin_amdgcn_mfma_f32_16x16x32_bf16(af[mt], bf[nt],
                                                                          acc[mt][nt], 0, 0, 0);
        }
#pragma unroll
        for (int mt = 0; mt < 2; mt++) {
            int c0 = wv * 32 + mt * 16 + lq * 4;
            float4 bb = *(const float4*)(b2 + c0);
#pragma unroll
            for (int nt = 0; nt < 4; nt++) {
                sv[mt][nt].x = swish_f(acc[mt][nt][0] + bb.x);
                sv[mt][nt].y = swish_f(acc[mt][nt][1] + bb.y);
                sv[mt][nt].z = swish_f(acc[mt][nt][2] + bb.z);
                sv[mt][nt].w = swish_f(acc[mt][nt][3] + bb.w);
            }
        }
    }
    __syncthreads();   // everyone done reading M -> buffer becomes S_t

    // ---- write S_t transposed [c][e] ----
#pragma unroll
    for (int mt = 0; mt < 2; mt++) {
        int c0 = wv * 32 + mt * 16 + lq * 4;
#pragma unroll
        for (int nt = 0; nt < 4; nt++) {
            int e = nt * 16 + lr;
            St[(c0 + 0) * EP + e] = sv[mt][nt].x;
            St[(c0 + 1) * EP + e] = sv[mt][nt].y;
            St[(c0 + 2) * EP + e] = sv[mt][nt].z;
            St[(c0 + 3) * EP + e] = sv[mt][nt].w;
        }
    }
    __syncthreads();

    // ---- segmented reduction: vector-load 32 contiguous values, register scan ----
    {
        const int c = tid & 127;
        const int half = tid >> 7;
        const int eb = half * 32;
        float v[32];
        const float* row = St + c * EP + eb;
#pragma unroll
        for (int q = 0; q < 8; q++) *(float4*)&v[q * 4] = *(const float4*)&row[q * 4];
        int cur = s_dst[eb];
        float acc = v[0];
#pragma unroll
        for (int i = 1; i < 32; i++) {
            int dn = s_dst[eb + i];
            if (dn != cur) {
                atomicAdd(agg + (size_t)cur * 128 + c, acc);
                acc = v[i];
                cur = dn;
            } else {
                acc += v[i];
            }
        }
        atomicAdd(agg + (size_t)cur * 128 + c, acc);
    }
}

// ---------------- Node MLP (MFMA, single LDS buffer, 4 blocks/CU) ----------------
__global__ __launch_bounds__(256, 4) void node_mlp_mfma(
    float* __restrict__ x, short* __restrict__ xb, const float* __restrict__ agg,
    const short* __restrict__ W1T, const float* __restrict__ b1,
    const short* __restrict__ W2T, const float* __restrict__ b2) {
    __shared__ __align__(16) short X[64 * MP];
    const int tid = threadIdx.x;
    const int n0 = blockIdx.x * 64;
    const int wv = tid >> 6;
    const int ln = tid & 63;
    const int lr = ln & 15;
    const int lq = ln >> 4;

    {
        int row = tid >> 2, p = tid & 3;
        int gn = n0 + row;
        if (gn < N_NODES) {
            const int4* xp = (const int4*)(xb + (size_t)gn * 128);
#pragma unroll
            for (int q = 0; q < 4; q++) {
                int c = p * 4 + q;
                *(int4*)(X + row * MP + c * 8) = xp[c];
            }
            const float4* ap = (const float4*)(agg + (size_t)gn * 128);
#pragma unroll
            for (int q = 0; q < 4; q++) {
                float4 f0 = ap[p * 8 + q * 2];
                float4 f1 = ap[p * 8 + q * 2 + 1];
                bh8 s;
                s[0] = f2bf(f0.x); s[1] = f2bf(f0.y); s[2] = f2bf(f0.z); s[3] = f2bf(f0.w);
                s[4] = f2bf(f1.x); s[5] = f2bf(f1.y); s[6] = f2bf(f1.z); s[7] = f2bf(f1.w);
                *(bh8*)(X + row * MP + 128 + p * 32 + q * 8) = s;
            }
        } else {
            int4 z4 = make_int4(0, 0, 0, 0);
#pragma unroll
            for (int q = 0; q < 8; q++) *(int4*)(X + row * MP + (p * 8 + q) * 8) = z4;
        }
    }
    __syncthreads();

    bh4 hv[4][4];
    {
        f32x4 acc[4][4];
#pragma unroll
        for (int a = 0; a < 4; a++)
#pragma unroll
            for (int b = 0; b < 4; b++) acc[a][b] = (f32x4)(0.f);

        const short* a_base = W1T + (size_t)(wv * 64 + lr) * 256 + lq * 8;
        for (int ks = 0; ks < 256; ks += 32) {
            bh8 af[4], bf[4];
#pragma unroll
            for (int mt = 0; mt < 4; mt++) af[mt] = *(const bh8*)(a_base + mt * 16 * 256 + ks);
#pragma unroll
            for (int nt = 0; nt < 4; nt++)
                bf[nt] = *(const bh8*)(X + (nt * 16 + lr) * MP + ks + lq * 8);
#pragma unroll
            for (int mt = 0; mt < 4; mt++)
#pragma unroll
                for (int nt = 0; nt < 4; nt++)
                    acc[mt][nt] = __builtin_amdgcn_mfma_f32_16x16x32_bf16(af[mt], bf[nt],
                                                                          acc[mt][nt], 0, 0, 0);
        }
#pragma unroll
        for (int mt = 0; mt < 4; mt++) {
            int h0 = wv * 64 + mt * 16 + lq * 4;
            float4 bb = *(const float4*)(b1 + h0);
#pragma unroll
            for (int nt = 0; nt < 4; nt++) {
                hv[mt][nt][0] = f2bf(swish_f(acc[mt][nt][0] + bb.x));
                hv[mt][nt][1] = f2bf(swish_f(acc[mt][nt][1] + bb.y));
                hv[mt][nt][2] = f2bf(swish_f(acc[mt][nt][2] + bb.z));
                hv[mt][nt][3] = f2bf(swish_f(acc[mt][nt][3] + bb.w));
            }
        }
    }
    __syncthreads();   // done reading A -> buffer becomes H

#pragma unroll
    for (int mt = 0; mt < 4; mt++) {
        int h0 = wv * 64 + mt * 16 + lq * 4;
#pragma unroll
        for (int nt = 0; nt < 4; nt++) {
            int e = nt * 16 + lr;
            *(bh4*)(X + e * MP + h0) = hv[mt][nt];
        }
    }
    __syncthreads();

    {
        f32x4 acc[2][4];
#pragma unroll
        for (int a = 0; a < 2; a++)
#pragma unroll
            for (int b = 0; b < 4; b++) acc[a][b] = (f32x4)(0.f);

        const short* a_base = W2T + (size_t)(wv * 32 + lr) * 256 + lq * 8;
        for (int ks = 0; ks < 256; ks += 32) {
            bh8 af[2], bf[4];
#pragma unroll
            for (int mt = 0; mt < 2; mt++) af[mt] = *(const bh8*)(a_base + mt * 16 * 256 + ks);
#pragma unroll
            for (int nt = 0; nt < 4; nt++)
                bf[nt] = *(const bh8*)(X + (nt * 16 + lr) * MP + ks + lq * 8);
#pragma unroll
            for (int mt = 0; mt < 2; mt++)
#pragma unroll
                for (int nt = 0; nt < 4; nt++)
                    acc[mt][nt] = __builtin_amdgcn_mfma_f32_16x16x32_bf16(af[mt], bf[nt],
                                                                          acc[mt][nt], 0, 0, 0);
        }
#pragma unroll
        for (int mt = 0; mt < 2; mt++) {
            int c0 = wv * 32 + mt * 16 + lq * 4;
            float4 bb = *(const float4*)(b2 + c0);
#pragma unroll
            for (int nt = 0; nt < 4; nt++) {
                int nl = nt * 16 + lr;
                int gn = n0 + nl;
                if (gn < N_NODES) {
                    float4 xv = *(const float4*)(x + (size_t)gn * 128 + c0);
                    float4 nv;
                    nv.x = xv.x + acc[mt][nt][0] + bb.x;
                    nv.y = xv.y + acc[mt][nt][1] + bb.y;
                    nv.z = xv.z + acc[mt][nt][2] + bb.z;
                    nv.w = xv.w + acc[mt][nt][3] + bb.w;
                    *(float4*)(x + (size_t)gn * 128 + c0) = nv;
                    bh4 pk;
                    pk[0] = f2bf(nv.x); pk[1] = f2bf(nv.y); pk[2] = f2bf(nv.z); pk[3] = f2bf(nv.w);
                    *(bh4*)(xb + (size_t)gn * 128 + c0) = pk;
                }
            }
        }
    }
}

// ---------------- Output head, atomic-free 3-stage ----------------
__global__ __launch_bounds__(256, 4) void out_stage1(
    const float* __restrict__ x, const float* __restrict__ w1, const float* __restrict__ b1,
    const float* __restrict__ w2, const float* __restrict__ b2, float* __restrict__ sval) {
    __shared__ float xr[32][128];
    __shared__ float red[4][32];
    const int tid = threadIdx.x;
    const int n0 = blockIdx.x * 32;

    {
        const float4* xs = (const float4*)(x + (size_t)n0 * 128);
        if (n0 + 32 <= N_NODES) {
#pragma unroll
            for (int q = 0; q < 4; q++) {
                int i = tid + q * 256;
                ((float4*)xr)[i] = xs[i];
            }
        } else {
#pragma unroll
            for (int q = 0; q < 4; q++) {
                int i = tid + q * 256;
                int nn = i >> 5;
                ((float4*)xr)[i] = (n0 + nn < N_NODES) ? xs[i] : make_float4(0.f, 0.f, 0.f, 0.f);
            }
        }
    }
    __syncthreads();

    float acc[32];
#pragma unroll
    for (int nn = 0; nn < 32; nn++) acc[nn] = 0.f;

    for (int k = 0; k < 128; k += 4) {
        float w_[4];
#pragma unroll
        for (int kk = 0; kk < 4; kk++) w_[kk] = w1[(size_t)(k + kk) * 256 + tid];
#pragma unroll
        for (int nn = 0; nn < 32; nn++) {
            float4 xv = *(const float4*)&xr[nn][k];
            acc[nn] += xv.x * w_[0] + xv.y * w_[1] + xv.z * w_[2] + xv.w * w_[3];
        }
    }

    const float bb = b1[tid];
    const float wc = w2[tid];
    const int lane = tid & 63, wvi = tid >> 6;
#pragma unroll
    for (int nn = 0; nn < 32; nn++) {
        float v = swish_f(acc[nn] + bb) * wc;
#pragma unroll
        for (int off = 32; off > 0; off >>= 1) v += __shfl_down(v, off, 64);
        if (lane == 0) red[wvi][nn] = v;
    }
    __syncthreads();
    if (tid < 32) {
        int gn = n0 + tid;
        if (gn < N_NODES)
            sval[gn] = red[0][tid] + red[1][tid] + red[2][tid] + red[3][tid] + b2[0];
    }
}

__global__ void out_stage2(const float* __restrict__ sval, const int* __restrict__ batch,
                           float* __restrict__ partial) {
    __shared__ float part[N_GRAPHS];
    const int tid = threadIdx.x;
    if (tid < N_GRAPHS) part[tid] = 0.f;
    __syncthreads();
    const int per_block = (N_NODES + OB2 - 1) / OB2;
    const int start = blockIdx.x * per_block;
    const int end = min(start + per_block, N_NODES);
    const int per_thread = (per_block + 255) / 256;
    int s = start + tid * per_thread;
    int e = min(s + per_thread, end);
    if (s < e) {
        int g = batch[s];
        float a = sval[s];
        for (int n = s + 1; n < e; n++) {
            int gg = batch[n];
            float v = sval[n];
            if (gg != g) {
                atomicAdd(&part[g], a);
                a = v;
                g = gg;
            } else {
                a += v;
            }
        }
        atomicAdd(&part[g], a);
    }
    __syncthreads();
    if (tid < N_GRAPHS) partial[blockIdx.x * N_GRAPHS + tid] = part[tid];
}

__global__ void out_stage3(const float* __restrict__ partial, float* __restrict__ out) {
    int g = threadIdx.x;
    if (g >= N_GRAPHS) return;
    float s = 0.f;
    for (int b = 0; b < OB2; b++) s += partial[b * N_GRAPHS + g];
    out[g] = s;
}

extern "C" void kernel_launch(void* const* d_in, const int* in_sizes, int n_in,
                              void* d_out, int out_size, void* d_ws, size_t ws_size,
                              hipStream_t stream) {
    const float* positions = (const float*)d_in[0];
    const float* edge_shift = (const float*)d_in[1];
    const float* lattice = (const float*)d_in[2];
    const int* atomic_numbers = (const int*)d_in[3];
    const int* edge_index = (const int*)d_in[4];
    const int* batch = (const int*)d_in[5];
    const float* embed_w = (const float*)d_in[6];
    const float* edge_w1 = (const float*)d_in[7];
    const float* edge_b1 = (const float*)d_in[8];
    const float* edge_w2 = (const float*)d_in[9];
    const float* edge_b2 = (const float*)d_in[10];
    const float* node_w1 = (const float*)d_in[11];
    const float* node_b1 = (const float*)d_in[12];
    const float* node_w2 = (const float*)d_in[13];
    const float* node_b2 = (const float*)d_in[14];
    const float* out_w1 = (const float*)d_in[15];
    const float* out_b1 = (const float*)d_in[16];
    const float* out_w2 = (const float*)d_in[17];
    const float* out_b2 = (const float*)d_in[18];

    // workspace layout
    float* ws = (float*)d_ws;
    float* x = ws;                               // N*128 f32
    float* agg = x + (size_t)N_NODES * 128;      // N*128 f32
    float* d2 = agg + (size_t)N_NODES * 128;     // E f32
    short* xb = (short*)(d2 + N_EDGES);          // N*128 bf16
    short* eW1T = xb + (size_t)N_NODES * 128;    // 3*256*288
    short* eW2T = eW1T + 3 * 256 * 288;          // 3*128*256
    short* nW1T = eW2T + 3 * 128 * 256;          // 3*256*256
    short* nW2T = nW1T + 3 * 256 * 256;          // 3*128*256
    int* deg = (int*)(nW2T + 3 * 128 * 256);     // N
    int* fillc = deg + N_NODES;                  // N
    int* sc = fillc + N_NODES;                   // N
    int* bsum = sc + N_NODES;                    // 128
    int* esorted = bsum + 128;                   // E
    int* rowptr = esorted + N_EDGES;             // N+1
    float* sval = (float*)(rowptr + N_NODES + 1);  // N
    float* partial = sval + N_NODES;               // OB2*N_GRAPHS

    (void)hipMemsetAsync(deg, 0, N_NODES * sizeof(int), stream);
    (void)hipMemsetAsync(fillc, 0, N_NODES * sizeof(int), stream);

    // weight transpose+cvt (tiny)
    {
        int t1 = 3 * 256 * 288;
        cvt_wT_kernel<<<(t1 + 255) / 256, 256, 0, stream>>>(edge_w1, eW1T, 257, 256, 288, t1);
        int t2 = 3 * 128 * 256;
        cvt_wT_kernel<<<(t2 + 255) / 256, 256, 0, stream>>>(edge_w2, eW2T, 256, 128, 256, t2);
        int t3 = 3 * 256 * 256;
        cvt_wT_kernel<<<(t3 + 255) / 256, 256, 0, stream>>>(node_w1, nW1T, 256, 256, 256, t3);
        cvt_wT_kernel<<<(t2 + 255) / 256, 256, 0, stream>>>(node_w2, nW2T, 256, 128, 256, t2);
    }

    prep_kernel<<<(N_EDGES + 255) / 256, 256, 0, stream>>>(positions, edge_shift, lattice,
                                                           edge_index, batch, d2);
    embed_kernel<<<(N_NODES * 128) / 256, 256, 0, stream>>>(embed_w, atomic_numbers, x, xb);

    // CSR counting sort by dst
    {
        int nscan = (N_NODES + SCAN_BS - 1) / SCAN_BS;
        hist_kernel<<<(N_EDGES + 255) / 256, 256, 0, stream>>>(edge_index, deg);
        scan1_kernel<<<nscan, SCAN_BS, 0, stream>>>(deg, sc, bsum, N_NODES);
        scan2_kernel<<<1, 128, 0, stream>>>(bsum, nscan);
        scan3_kernel<<<(N_NODES + SCAN_BS) / SCAN_BS + 1, SCAN_BS, 0, stream>>>(
            sc, deg, bsum, rowptr, N_NODES, N_EDGES);
        fill_kernel<<<(N_EDGES + 255) / 256, 256, 0, stream>>>(edge_index, rowptr, fillc,
                                                               esorted);
    }

    for (int l = 0; l < N_LAYERS; l++) {
        (void)hipMemsetAsync(agg, 0, (size_t)N_NODES * 128 * sizeof(float), stream);
        edge_mlp_mfma<<<N_EDGES / 64, 256, 0, stream>>>(
            xb, d2, edge_index, esorted,
            eW1T + (size_t)l * 256 * 288, edge_b1 + (size_t)l * 256,
            eW2T + (size_t)l * 128 * 256, edge_b2 + (size_t)l * 128, agg);
        node_mlp_mfma<<<(N_NODES + 63) / 64, 256, 0, stream>>>(
            x, xb, agg,
            nW1T + (size_t)l * 256 * 256, node_b1 + (size_t)l * 256,
            nW2T + (size_t)l * 128 * 256, node_b2 + (size_t)l * 128);
    }
    out_stage1<<<(N_NODES + 31) / 32, 256, 0, stream>>>(x, out_w1, out_b1, out_w2, out_b2, sval);
    out_stage2<<<OB2, 256, 0, stream>>>(sval, batch, partial);
    out_stage3<<<1, 64, 0, stream>>>(partial, (float*)d_out);
}